// Round 16
// baseline (2715.484 us; speedup 1.0000x reference)
//
#include <hip/hip_runtime.h>
#include <math.h>

#define DEV __device__ __forceinline__

typedef __attribute__((ext_vector_type(8))) short short8;
typedef __attribute__((ext_vector_type(4))) short short4v;
typedef __attribute__((ext_vector_type(4))) float f32x4;
typedef __attribute__((ext_vector_type(8))) __bf16 bf16x8;

DEV float bf2f(unsigned short u) {
    union { unsigned int i; float f; } c; c.i = ((unsigned int)u) << 16; return c.f;
}
DEV unsigned short f2bf(float f) {
    union { float f; unsigned int i; } c; c.f = f;
    unsigned int u = c.i;
    u += 0x7fffu + ((u >> 16) & 1u);   // RNE
    return (unsigned short)(u >> 16);
}
DEV float gelu_exact(float x) { return 0.5f * x * (1.0f + erff(x * 0.70710678118654752f)); }

DEV f32x4 MF(bf16x8 a, bf16x8 b, f32x4 c) {
    return __builtin_amdgcn_mfma_f32_16x16x32_bf16(a, b, c, 0, 0, 0);
}

#define GLL16(g, l)                                                                   \
    __builtin_amdgcn_global_load_lds(                                                \
        (const __attribute__((address_space(1))) unsigned int*)(g),                  \
        (__attribute__((address_space(3))) unsigned int*)(l), 16, 0, 0)

// blocked-KV geometry: per (layer,part) slot = 128 bt x 16 h x 256 f x 64 d u16
#define KV_HSTR   16384ull                 // h stride (256*64)
#define KV_BTSTR  262144ull                // bt stride (16*16384)
#define KV_PSLOT  33554432ull              // (s*2+p) slot stride (128*262144)

// ---------------------------------------------------------------------------
// Weight transpose + f32->bf16 convert: in (K,N) f32 row-major -> out (N,K) bf16.
// ---------------------------------------------------------------------------
__global__ __launch_bounds__(256)
void transpose_w(const float* __restrict__ in, unsigned short* __restrict__ out,
                 const float* __restrict__ rowscale, float uscale,
                 int K, int N, size_t inStride, size_t outStride, int scaleStride)
{
    __shared__ float tile[64][65];
    in  += (size_t)blockIdx.z * inStride;
    out += (size_t)blockIdx.z * outStride;
    const int k0 = blockIdx.y * 64, n0 = blockIdx.x * 64;
    const int tid = threadIdx.x;
    const int c = tid & 63;
#pragma unroll
    for (int i = 0; i < 16; ++i) {
        int rr = (i << 2) + (tid >> 6);
        float v = in[(size_t)(k0 + rr) * N + n0 + c];
        if (rowscale) v *= rowscale[(size_t)blockIdx.z * scaleStride + k0 + rr];
        tile[rr][c] = v * uscale;
    }
    __syncthreads();
#pragma unroll
    for (int i = 0; i < 16; ++i) {
        int rr = (i << 2) + (tid >> 6);
        out[(size_t)(n0 + rr) * K + k0 + c] = f2bf(tile[c][rr]);
    }
}

// bias_kv[d][c] = sum_r ln_media_b[d][r] * w[d][r][c]
__global__ __launch_bounds__(256)
void fold_bias(const float* __restrict__ wk, const float* __restrict__ wv,
               const float* __restrict__ bmed, float* __restrict__ biaskv)
{
    const int d = blockIdx.x >> 3;
    const int rem = blockIdx.x & 7;
    const int part = rem >> 2;
    const int chunk = rem & 3;
    const float* w = (part ? wv : wk) + (size_t)d * 1024 * 1024 + chunk * 256 + threadIdx.x;
    const float* b = bmed + d * 1024;
    float acc = 0.f;
    for (int r = 0; r < 1024; ++r) acc += b[r] * w[(size_t)r * 1024];
    biaskv[d * 2048 + part * 1024 + chunk * 256 + threadIdx.x] = acc;
}

__global__ __launch_bounds__(256)
void convert_bf16(const float* __restrict__ in, unsigned short* __restrict__ out, size_t n4)
{
    size_t i = (size_t)blockIdx.x * 256 + threadIdx.x;
    if (i >= n4) return;
    float4 v = ((const float4*)in)[i];
    ushort4 u;
    u.x = f2bf(v.x); u.y = f2bf(v.y); u.z = f2bf(v.z); u.w = f2bf(v.w);
    ((ushort4*)out)[i] = u;
}

__global__ __launch_bounds__(256)
void init_x(const float* __restrict__ lat, float* __restrict__ x)
{
    const int row = blockIdx.x;
    ((float4*)x)[(size_t)row * 256 + threadIdx.x] =
        ((const float4*)lat)[(size_t)(row & 255) * 256 + threadIdx.x];
}

// ---------------------------------------------------------------------------
// LayerNorm over D=1024, one row per block. INBF: input is bf16 (u16).
// ---------------------------------------------------------------------------
template<bool AFFINE, bool OUTBF, bool INBF>
__global__ __launch_bounds__(256)
void ln_k(const void* __restrict__ in_, const float* __restrict__ g,
          const float* __restrict__ b, void* __restrict__ out)
{
    const int row = blockIdx.x;
    const int tid = threadIdx.x;
    float4 v;
    if (INBF) {
        ushort4 u = ((const ushort4*)((const unsigned short*)in_ + (size_t)row * 1024))[tid];
        v.x = bf2f(u.x); v.y = bf2f(u.y); v.z = bf2f(u.z); v.w = bf2f(u.w);
    } else {
        v = ((const float4*)((const float*)in_ + (size_t)row * 1024))[tid];
    }
    float s  = v.x + v.y + v.z + v.w;
    float ss = v.x * v.x + v.y * v.y + v.z * v.z + v.w * v.w;
#pragma unroll
    for (int o = 32; o > 0; o >>= 1) { s += __shfl_down(s, o); ss += __shfl_down(ss, o); }
    __shared__ float red[8];
    if ((tid & 63) == 0) { red[tid >> 6] = s; red[4 + (tid >> 6)] = ss; }
    __syncthreads();
    const float sum  = red[0] + red[1] + red[2] + red[3];
    const float ssum = red[4] + red[5] + red[6] + red[7];
    const float mean = sum * (1.0f / 1024.0f);
    const float var  = ssum * (1.0f / 1024.0f) - mean * mean;
    const float rs   = rsqrtf(var + 1e-5f);
    float o0 = (v.x - mean) * rs, o1 = (v.y - mean) * rs;
    float o2 = (v.z - mean) * rs, o3 = (v.w - mean) * rs;
    if (AFFINE) {
        float4 gv = ((const float4*)g)[tid];
        float4 bv = ((const float4*)b)[tid];
        o0 = o0 * gv.x + bv.x; o1 = o1 * gv.y + bv.y;
        o2 = o2 * gv.z + bv.z; o3 = o3 * gv.w + bv.w;
    }
    if (OUTBF) {
        ushort4 u; u.x = f2bf(o0); u.y = f2bf(o1); u.z = f2bf(o2); u.w = f2bf(o3);
        ((ushort4*)out)[(size_t)row * 256 + tid] = u;
    } else {
        float4 ov; ov.x = o0; ov.y = o1; ov.z = o2; ov.w = o3;
        ((float4*)out)[(size_t)row * 256 + tid] = ov;
    }
}

enum { E_BF16 = 0, E_BIAS_BF16, E_BIAS_GELU_BF16, E_BIAS_TPOS_BF16, E_ADD_F32, E_BIAS_ADD_F32 };

// ---------------------------------------------------------------------------
// Big-shape GEMM: 128x128 tile, BK=64, 4 waves, 32 KB LDS (~3 blocks/CU),
// global_load_lds with pre-swizzled source, conflict-free swizzled
// ds_read_b128 (cp = c ^ (row&7)), bijective XCD swizzle.
// MODE 0: flat output. MODE 1 ("grouped KV", measured 1.63x faster/layer):
// N = G*2048, grid = G*4096; per-XCD iteration s-group -> by -> bx keeps each
// group's B panel L2-resident. MODE-1 epilogue writes HEAD-BLOCKED layout
// [(s*2+p)*128+bt][h][f][d] so attention reads contiguous 32 KB tiles.
// C(M,N) = A(M,K) @ Bt(N,K)^T.
// ---------------------------------------------------------------------------
template<int EPI, int MODE>
__global__ __launch_bounds__(256, 2)
void gemm_bt(const unsigned short* __restrict__ A, const unsigned short* __restrict__ Bt,
             void* __restrict__ Out,
             const float* __restrict__ bias, const float* __restrict__ addsrc,
             const float* __restrict__ tpos,
             int M, int N, int K)
{
    __shared__ unsigned short lds[2 * 128 * 64];
    const int tid  = threadIdx.x;
    const int wave = tid >> 6, lane = tid & 63;
    const int nbx  = N >> 7;

    int by, bx;
    if (MODE == 1) {
        const int u = blockIdx.x >> 3;
        const int s = u >> 9;                  // depth group
        const int v = u & 511;
        by = (blockIdx.x & 7) * 32 + (v >> 4); // 0..255
        bx = s * 16 + (v & 15);
    } else {
        const int nwg = gridDim.x;
        int bid = blockIdx.x;
        int wg = ((nwg & 7) == 0) ? ((bid & 7) * (nwg >> 3) + (bid >> 3)) : bid;
        by = wg / nbx; bx = wg % nbx;
    }

    const int swz = ((lane & 7) ^ (lane >> 3)) * 8;
    const unsigned short* gA = A  + (size_t)(by * 128 + (lane >> 3)) * K + swz;
    const unsigned short* gB = Bt + (size_t)(bx * 128 + (lane >> 3)) * K + swz;

    const int wr = wave >> 1, wc = wave & 1;
    f32x4 acc[4][4] = {};

    unsigned short* ldsA = lds;
    unsigned short* ldsB = lds + 128 * 64;

    const int off0 = (((lane >> 4)    ) ^ (lane & 7)) * 8;
    const int off1 = (((lane >> 4) | 4) ^ (lane & 7)) * 8;
    const unsigned short* la = ldsA + (wr * 64 + (lane & 15)) * 64;
    const unsigned short* lb = ldsB + (wc * 64 + (lane & 15)) * 64;

    for (int kt = 0; kt < K; kt += 64) {
#pragma unroll
        for (int j = 0; j < 4; ++j) {
            const int chunk = (j << 2) + wave;   // wave-uniform
            GLL16(gA + (size_t)chunk * 8 * K + kt, ldsA + chunk * 512);
            GLL16(gB + (size_t)chunk * 8 * K + kt, ldsB + chunk * 512);
        }
        __syncthreads();
#pragma unroll
        for (int kk = 0; kk < 2; ++kk) {
            const int offk = kk ? off1 : off0;
            bf16x8 a[4], b[4];
#pragma unroll
            for (int m = 0; m < 4; ++m) a[m] = *(const bf16x8*)(la + m * 1024 + offk);
#pragma unroll
            for (int n = 0; n < 4; ++n) b[n] = *(const bf16x8*)(lb + n * 1024 + offk);
#pragma unroll
            for (int m = 0; m < 4; ++m)
#pragma unroll
                for (int n = 0; n < 4; ++n)
                    acc[m][n] = MF(a[m], b[n], acc[m][n]);
        }
        __syncthreads();
    }

    // epilogue: C/D layout col = lane&15, row = (lane>>4)*4 + reg  [m89-verified]
    const int r0 = by * 128 + wr * 64 + (lane >> 4) * 4;
    const int c0 = bx * 128 + wc * 64 + (lane & 15);
#pragma unroll
    for (int m = 0; m < 4; ++m) {
#pragma unroll
        for (int n = 0; n < 4; ++n) {
            const int c = c0 + n * 16;
            float bv = 0.f;
            if (EPI == E_BIAS_BF16 || EPI == E_BIAS_GELU_BF16 ||
                EPI == E_BIAS_TPOS_BF16 || EPI == E_BIAS_ADD_F32)
                bv = bias[c];
            // blocked-KV decomposition (MODE 1)
            const int s  = c >> 11;
            const int cx = c & 2047;
            const int p  = cx >> 10, hx = (cx >> 6) & 15, d = cx & 63;
#pragma unroll
            for (int j = 0; j < 4; ++j) {
                const int r = r0 + m * 16 + j;
                float v = acc[m][n][j] + bv;
                if (EPI == E_BIAS_GELU_BF16) v = gelu_exact(v);
                if (EPI == E_BIAS_TPOS_BF16) v += tpos[(((unsigned)r >> 8) & 15) * 1024 + c];
                if (EPI == E_ADD_F32 || EPI == E_BIAS_ADD_F32) v += addsrc[(size_t)r * N + c];
                if (MODE == 1) {
                    const int bt = r >> 8, f = r & 255;
                    ((unsigned short*)Out)[(size_t)((s * 2 + p) * 128 + bt) * KV_BTSTR +
                                           (size_t)hx * KV_HSTR + f * 64 + d] = f2bf(v);
                } else if (EPI == E_ADD_F32 || EPI == E_BIAS_ADD_F32) {
                    ((float*)Out)[(size_t)r * N + c] = v;
                } else {
                    ((unsigned short*)Out)[(size_t)r * N + c] = f2bf(v);
                }
            }
        }
    }
}

// ---------------------------------------------------------------------------
// Latent-stack GEMM: 64x128 tile, BK=64, 4 waves, 24 KB LDS, m97 skeleton +
// zero-conflict swizzle (r4-verified). Used for qkv (grid 768), ffn1 (1024).
// ---------------------------------------------------------------------------
template<int EPI>
__global__ __launch_bounds__(256, 4)
void gemm64(const unsigned short* __restrict__ A, const unsigned short* __restrict__ Bt,
            void* __restrict__ Out,
            const float* __restrict__ bias, const float* __restrict__ addsrc,
            int M, int N, int K)
{
    __shared__ unsigned short lds[64 * 64 + 128 * 64];
    const int tid  = threadIdx.x;
    const int wave = tid >> 6, lane = tid & 63;
    const int nbx  = N >> 7;

    const int nwg = gridDim.x;
    int bid = blockIdx.x;
    int wg = ((nwg & 7) == 0) ? ((bid & 7) * (nwg >> 3) + (bid >> 3)) : bid;
    const int by = wg / nbx, bx = wg % nbx;

    const int swz = ((lane & 7) ^ (lane >> 3)) * 8;
    const unsigned short* gA = A  + (size_t)(by * 64  + (lane >> 3)) * K + swz;
    const unsigned short* gB = Bt + (size_t)(bx * 128 + (lane >> 3)) * K + swz;

    const int wr = wave >> 1, wc = wave & 1;
    f32x4 acc[2][4] = {};

    unsigned short* ldsA = lds;
    unsigned short* ldsB = lds + 64 * 64;

    const int off0 = (((lane >> 4)    ) ^ (lane & 7)) * 8;
    const int off1 = (((lane >> 4) | 4) ^ (lane & 7)) * 8;
    const unsigned short* la = ldsA + (wr * 32 + (lane & 15)) * 64;
    const unsigned short* lb = ldsB + (wc * 64 + (lane & 15)) * 64;

    for (int kt = 0; kt < K; kt += 64) {
        GLL16(gA + (size_t)(wave)     * 8 * K + kt, ldsA + (wave)      * 512);
        GLL16(gA + (size_t)(4 + wave) * 8 * K + kt, ldsA + (4 + wave)  * 512);
#pragma unroll
        for (int j = 0; j < 4; ++j) {
            const int chunk = (j << 2) + wave;
            GLL16(gB + (size_t)chunk * 8 * K + kt, ldsB + chunk * 512);
        }
        __syncthreads();
#pragma unroll
        for (int kk = 0; kk < 2; ++kk) {
            const int offk = kk ? off1 : off0;
            bf16x8 a[2], b[4];
#pragma unroll
            for (int m = 0; m < 2; ++m) a[m] = *(const bf16x8*)(la + m * 1024 + offk);
#pragma unroll
            for (int n = 0; n < 4; ++n) b[n] = *(const bf16x8*)(lb + n * 1024 + offk);
#pragma unroll
            for (int m = 0; m < 2; ++m)
#pragma unroll
                for (int n = 0; n < 4; ++n)
                    acc[m][n] = MF(a[m], b[n], acc[m][n]);
        }
        __syncthreads();
    }

    const int r0 = by * 64 + wr * 32 + (lane >> 4) * 4;
    const int c0 = bx * 128 + wc * 64 + (lane & 15);
#pragma unroll
    for (int m = 0; m < 2; ++m) {
#pragma unroll
        for (int n = 0; n < 4; ++n) {
            const int c = c0 + n * 16;
#pragma unroll
            for (int j = 0; j < 4; ++j) {
                const int r = r0 + m * 16 + j;
                float v = acc[m][n][j];
                if (EPI == E_BIAS_BF16 || EPI == E_BIAS_GELU_BF16 || EPI == E_BIAS_ADD_F32)
                    v += bias[c];
                if (EPI == E_BIAS_GELU_BF16) v = gelu_exact(v);
                if (EPI == E_ADD_F32 || EPI == E_BIAS_ADD_F32) v += addsrc[(size_t)r * N + c];
                if (EPI == E_ADD_F32 || EPI == E_BIAS_ADD_F32)
                    ((float*)Out)[(size_t)r * N + c] = v;
                else
                    ((unsigned short*)Out)[(size_t)r * N + c] = f2bf(v);
            }
        }
    }
}

// ---------------------------------------------------------------------------
// Small-N GEMM: 64x64 tile, BK=64, 4 waves (wave-tile 32x32), 16 KB LDS ->
// 4 blocks/CU. For wo and ffn2 (N=1024): grid 512 (r9/r11 A/B-measured best).
// ---------------------------------------------------------------------------
template<int EPI>
__global__ __launch_bounds__(256, 4)
void gemm3232(const unsigned short* __restrict__ A, const unsigned short* __restrict__ Bt,
              void* __restrict__ Out,
              const float* __restrict__ bias, const float* __restrict__ addsrc,
              int M, int N, int K)
{
    __shared__ unsigned short lds[2 * 64 * 64];    // A then B, 16 KiB
    const int tid  = threadIdx.x;
    const int wave = tid >> 6, lane = tid & 63;
    const int nbx  = N >> 6;

    const int nwg = gridDim.x;
    int bid = blockIdx.x;
    int wg = ((nwg & 7) == 0) ? ((bid & 7) * (nwg >> 3) + (bid >> 3)) : bid;
    const int by = wg / nbx, bx = wg % nbx;

    const int swz = ((lane & 7) ^ (lane >> 3)) * 8;
    const unsigned short* gA = A  + (size_t)(by * 64 + (lane >> 3)) * K + swz;
    const unsigned short* gB = Bt + (size_t)(bx * 64 + (lane >> 3)) * K + swz;

    const int wr = wave >> 1, wc = wave & 1;
    f32x4 acc[2][2] = {};

    unsigned short* ldsA = lds;
    unsigned short* ldsB = lds + 64 * 64;

    const int off0 = (((lane >> 4)    ) ^ (lane & 7)) * 8;
    const int off1 = (((lane >> 4) | 4) ^ (lane & 7)) * 8;
    const unsigned short* la = ldsA + (wr * 32 + (lane & 15)) * 64;
    const unsigned short* lb = ldsB + (wc * 32 + (lane & 15)) * 64;

    for (int kt = 0; kt < K; kt += 64) {
        GLL16(gA + (size_t)(wave)     * 8 * K + kt, ldsA + (wave)      * 512);
        GLL16(gA + (size_t)(4 + wave) * 8 * K + kt, ldsA + (4 + wave)  * 512);
        GLL16(gB + (size_t)(wave)     * 8 * K + kt, ldsB + (wave)      * 512);
        GLL16(gB + (size_t)(4 + wave) * 8 * K + kt, ldsB + (4 + wave)  * 512);
        __syncthreads();
#pragma unroll
        for (int kk = 0; kk < 2; ++kk) {
            const int offk = kk ? off1 : off0;
            bf16x8 a[2], b[2];
#pragma unroll
            for (int m = 0; m < 2; ++m) a[m] = *(const bf16x8*)(la + m * 1024 + offk);
#pragma unroll
            for (int n = 0; n < 2; ++n) b[n] = *(const bf16x8*)(lb + n * 1024 + offk);
#pragma unroll
            for (int m = 0; m < 2; ++m)
#pragma unroll
                for (int n = 0; n < 2; ++n)
                    acc[m][n] = MF(a[m], b[n], acc[m][n]);
        }
        __syncthreads();
    }

    const int r0 = by * 64 + wr * 32 + (lane >> 4) * 4;
    const int c0 = bx * 64 + wc * 32 + (lane & 15);
#pragma unroll
    for (int m = 0; m < 2; ++m) {
#pragma unroll
        for (int n = 0; n < 2; ++n) {
            const int c = c0 + n * 16;
#pragma unroll
            for (int j = 0; j < 4; ++j) {
                const int r = r0 + m * 16 + j;
                float v = acc[m][n][j];
                if (EPI == E_BIAS_BF16 || EPI == E_BIAS_GELU_BF16 || EPI == E_BIAS_ADD_F32)
                    v += bias[c];
                if (EPI == E_BIAS_GELU_BF16) v = gelu_exact(v);
                if (EPI == E_ADD_F32 || EPI == E_BIAS_ADD_F32) v += addsrc[(size_t)r * N + c];
                if (EPI == E_ADD_F32 || EPI == E_BIAS_ADD_F32)
                    ((float*)Out)[(size_t)r * N + c] = v;
                else
                    ((unsigned short*)Out)[(size_t)r * N + c] = f2bf(v);
            }
        }
    }
}

// ---------------------------------------------------------------------------
// Attention v2: one block per (bt, head). Q=16, F=272, DH=64.
// LDS diet for 3 blocks/CU (__launch_bounds__(256,3)): sim stored bf16
// (8.7 KB) with qs (f32, dead after S1) overlaid inside it; kv keeps the
// conflict-free stride-72 padding. Total LDS = 39168+8736+256 = 48.2 KB.
// f32 softmax sum computed from unquantized p (only PV numerator is bf16).
// Media KV read from head-blocked layout (contiguous 32 KB per tile).
// ---------------------------------------------------------------------------
__global__ __launch_bounds__(256, 3)
void attn_k(const unsigned short* __restrict__ qkvl, const unsigned short* __restrict__ kbase,
            unsigned short* __restrict__ o)
{
    __shared__ unsigned short kv[272 * 72];        // 39168 B
    __shared__ unsigned short simqs[16 * 273];     // 8736 B: sim bf16; qs f32 overlay
    __shared__ float red[64];

    float* qs = (float*)simqs;                     // 16*68 f32 = 4352 B (dead after S1)
    unsigned short* sim = simqs;

    const int bt = blockIdx.x >> 4, h = blockIdx.x & 15;
    const int tid = threadIdx.x;
    const int lane = tid & 63, wave = tid >> 6;
    const int r = tid & 15, grp = tid >> 4;

    const unsigned short* kt = kbase + (size_t)bt * KV_BTSTR + (size_t)h * KV_HSTR;

    {
        const int qi = tid >> 4, d0 = (tid & 15) * 4;
        const unsigned short* src = qkvl + (size_t)(bt * 16 + qi) * 3072 + h * 64 + d0;
        qs[qi * 68 + d0 + 0] = bf2f(src[0]);
        qs[qi * 68 + d0 + 1] = bf2f(src[1]);
        qs[qi * 68 + d0 + 2] = bf2f(src[2]);
        qs[qi * 68 + d0 + 3] = bf2f(src[3]);
    }
#pragma unroll
    for (int i = 0; i < 9; ++i) {
        int idx = i * 256 + tid;
        if (idx < 2176) {
            int f = idx >> 3, cp = idx & 7;
            const unsigned short* src = (f < 256)
                ? kt + f * 64 + cp * 8
                : qkvl + (size_t)(bt * 16 + (f - 256)) * 3072 + 1024 + h * 64 + cp * 8;
            *(short8*)&kv[f * 72 + cp * 8] = *(const short8*)src;
        }
    }
    __syncthreads();                               // S0

    float p[17];
#pragma unroll
    for (int i = 0; i < 17; ++i) p[i] = 0.f;
#pragma unroll
    for (int d = 0; d < 64; d += 8) {
        float q8[8];
#pragma unroll
        for (int j = 0; j < 8; ++j) q8[j] = qs[r * 68 + d + j];
#pragma unroll
        for (int i = 0; i < 17; ++i) {
            short8 k8 = *(const short8*)&kv[(grp + i * 16) * 72 + d];
#pragma unroll
            for (int j = 0; j < 8; ++j) p[i] += q8[j] * bf2f((unsigned short)k8[j]);
        }
    }
    float mx = -3.0e38f;
#pragma unroll
    for (int i = 0; i < 17; ++i) mx = fmaxf(mx, p[i]);
    mx = fmaxf(mx, __shfl_xor(mx, 16));
    mx = fmaxf(mx, __shfl_xor(mx, 32));
    if (lane < 16) red[wave * 16 + lane] = mx;
    __syncthreads();                               // S1: qs reads + K reads complete
    const float rowmax = fmaxf(fmaxf(red[r], red[16 + r]), fmaxf(red[32 + r], red[48 + r]));

    float sm = 0.f;
#pragma unroll
    for (int i = 0; i < 17; ++i) { p[i] = __expf(p[i] - rowmax); sm += p[i]; }
    sm += __shfl_xor(sm, 16);
    sm += __shfl_xor(sm, 32);
#pragma unroll
    for (int i = 0; i < 17; ++i) sim[r * 273 + grp + i * 16] = f2bf(p[i]);   // overlays qs (safe after S1)
    __syncthreads();                               // S2: red(max) reads done
    if (lane < 16) red[wave * 16 + lane] = sm;
#pragma unroll
    for (int i = 0; i < 9; ++i) {
        int idx = i * 256 + tid;
        if (idx < 2176) {
            int f = idx >> 3, cp = idx & 7;
            const unsigned short* src = (f < 256)
                ? kt + KV_PSLOT + f * 64 + cp * 8
                : qkvl + (size_t)(bt * 16 + (f - 256)) * 3072 + 2048 + h * 64 + cp * 8;
            *(short8*)&kv[f * 72 + cp * 8] = *(const short8*)src;
        }
    }
    __syncthreads();                               // S3: sim + red(sum) + V ready
    const float inv = 1.0f / (red[r] + red[16 + r] + red[32 + r] + red[48 + r]);

    float o0 = 0.f, o1 = 0.f, o2 = 0.f, o3 = 0.f;
    for (int f = 0; f < 272; ++f) {
        float pv = bf2f(sim[r * 273 + f]);
        short4v v4 = *(const short4v*)&kv[f * 72 + grp * 4];
        o0 += pv * bf2f((unsigned short)v4[0]);
        o1 += pv * bf2f((unsigned short)v4[1]);
        o2 += pv * bf2f((unsigned short)v4[2]);
        o3 += pv * bf2f((unsigned short)v4[3]);
    }
    unsigned short* dst = o + (size_t)(bt * 16 + r) * 1024 + h * 64 + grp * 4;
    dst[0] = f2bf(o0 * inv);
    dst[1] = f2bf(o1 * inv);
    dst[2] = f2bf(o2 * inv);
    dst[3] = f2bf(o3 * inv);
}

// ---------------------------------------------------------------------------
extern "C" void kernel_launch(void* const* d_in, const int* in_sizes, int n_in,
                              void* d_out, int out_size, void* d_ws, size_t ws_size,
                              hipStream_t stream)
{
    const float* x_f      = (const float*)d_in[0];
    const float* goal_w1  = (const float*)d_in[1];
    const float* goal_b1  = (const float*)d_in[2];
    const float* goal_w2  = (const float*)d_in[3];
    const float* goal_b2  = (const float*)d_in[4];
    const float* latents  = (const float*)d_in[5];
    const float* tpos     = (const float*)d_in[6];
    const float* lnm_g    = (const float*)d_in[7];
    const float* lnm_b    = (const float*)d_in[8];
    const float* lnl_g    = (const float*)d_in[9];
    const float* lnl_b    = (const float*)d_in[10];
    const float* wq       = (const float*)d_in[11];
    const float* wk       = (const float*)d_in[12];
    const float* wv       = (const float*)d_in[13];
    const float* wo       = (const float*)d_in[14];
    const float* ffn_g    = (const float*)d_in[15];
    const float* ffn_b    = (const float*)d_in[16];
    const float* ffw1     = (const float*)d_in[17];
    const float* ffb1     = (const float*)d_in[18];
    const float* ffw2     = (const float*)d_in[19];
    const float* ffb2     = (const float*)d_in[20];
    const float* fin_g    = (const float*)d_in[21];
    const float* fin_b    = (const float*)d_in[22];

    char* ws = (char*)d_ws;
    size_t off = 0;
    auto alloc = [&](size_t bytes) -> char* {
        char* p = ws + off;
        off += (bytes + 255) & ~(size_t)255;
        return p;
    };
    typedef unsigned short u16;
    u16*   wg1t   = (u16*)  alloc(2048ull * 1280 * 2);
    u16*   wg2t   = (u16*)  alloc(1024ull * 2048 * 2);
    u16*   wqkvl  = (u16*)  alloc(6ull * 3072 * 1024 * 2);
    u16*   wkvm   = (u16*)  alloc(6ull * 2048 * 1024 * 2);
    u16*   wot    = (u16*)  alloc(6ull * 1024 * 1024 * 2);
    u16*   wf1t   = (u16*)  alloc(6ull * 4096 * 1024 * 2);
    u16*   wf2t   = (u16*)  alloc(6ull * 1024 * 4096 * 2);
    float* biaskv = (float*)alloc(6ull * 2048 * 4);
    float* xres   = (float*)alloc(2048ull * 1024 * 4);
    u16*   latn   = (u16*)  alloc(2048ull * 1024 * 2);
    u16*   qkvl   = (u16*)  alloc(2048ull * 3072 * 2);
    u16*   obuf   = (u16*)  alloc(2048ull * 1024 * 2);
    u16*   ffny   = (u16*)  alloc(2048ull * 1024 * 2);
    u16*   ffnmid = (u16*)  alloc(2048ull * 4096 * 2);
    u16*   bufB   = (u16*)  alloc(32768ull * 1024 * 2);   // goal output, bf16
    u16*   bufC   = (u16*)  alloc(41943040ull * 2);       // x_f bf16, then nf
    if (off > ws_size) return;
    // bufA last: grouped-KV buffer. Pick largest G in {6,3,2,1} that fits.
    const size_t singleBytes = 32768ull * 2048 * 2;       // per-layer KV = 134 MB
    int G = 1;
    if (off + 6 * singleBytes <= ws_size)      G = 6;
    else if (off + 3 * singleBytes <= ws_size) G = 3;
    else if (off + 2 * singleBytes <= ws_size) G = 2;
    u16* bufA = (u16*)alloc((size_t)G * singleBytes);
    if (off > ws_size) return;
    const int kvN = G * 2048;

    // ---- phase 0: conversions / folds ----
    convert_bf16<<<40960, 256, 0, stream>>>(x_f, bufC, 41943040ull / 4);
    transpose_w<<<dim3(32, 20, 1), 256, 0, stream>>>(goal_w1, wg1t, nullptr, 1.f, 1280, 2048, 0, 0, 0);
    transpose_w<<<dim3(16, 32, 1), 256, 0, stream>>>(goal_w2, wg2t, nullptr, 1.f, 2048, 1024, 0, 0, 0);
    transpose_w<<<dim3(16, 16, 6), 256, 0, stream>>>(wq, wqkvl,                nullptr, 0.125f, 1024, 1024, 1024ull*1024, 3072ull*1024, 0);
    transpose_w<<<dim3(16, 16, 6), 256, 0, stream>>>(wk, wqkvl + 1024ull*1024, nullptr, 1.f,    1024, 1024, 1024ull*1024, 3072ull*1024, 0);
    transpose_w<<<dim3(16, 16, 6), 256, 0, stream>>>(wv, wqkvl + 2048ull*1024, nullptr, 1.f,    1024, 1024, 1024ull*1024, 3072ull*1024, 0);
    transpose_w<<<dim3(16, 16, 6), 256, 0, stream>>>(wk, wkvm,                 lnm_g,   1.f,    1024, 1024, 1024ull*1024, 2048ull*1024, 1024);
    transpose_w<<<dim3(16, 16, 6), 256, 0, stream>>>(wv, wkvm + 1024ull*1024,  lnm_g,   1.f,    1024, 1024, 1024ull*1024, 2048ull*1024, 1024);
    transpose_w<<<dim3(16, 16, 6), 256, 0, stream>>>(wo, wot,                  nullptr, 1.f,    1024, 1024, 1024ull*1024, 1024ull*1024, 0);
    transpose_w<<<dim3(64, 16, 6), 256, 0, stream>>>(ffw1, wf1t,               nullptr, 1.f,    1024, 4096, 4096ull*1024, 4096ull*1024, 0);
    transpose_w<<<dim3(16, 64, 6), 256, 0, stream>>>(ffw2, wf2t,               nullptr, 1.f,    4096, 1024, 4096ull*1024, 4096ull*1024, 0);
    fold_bias<<<48, 256, 0, stream>>>(wk, wv, lnm_b, biaskv);
    init_x<<<2048, 256, 0, stream>>>(latents, xres);

    // ---- goal MLP ----
    gemm_bt<E_BIAS_GELU_BF16, 0><<<256 * 16, 256, 0, stream>>>(bufC, wg1t, bufA, goal_b1, nullptr, nullptr, 32768, 2048, 1280);
    gemm_bt<E_BIAS_TPOS_BF16, 0><<<256 * 8, 256, 0, stream>>>(bufA, wg2t, bufB, goal_b2, nullptr, tpos, 32768, 1024, 2048);
    ln_k<false, true, true><<<32768, 256, 0, stream>>>(bufB, nullptr, nullptr, bufC);   // nf

    // ---- depth loop (grouped KV: one merged GEMM per G layers, blocked layout) ----
    for (int i = 0; i < 6; ++i) {
        const u16* wqkvl_i = wqkvl + (size_t)i * 3072 * 1024;
        const u16* wot_i   = wot   + (size_t)i * 1024 * 1024;
        const u16* wf1_i   = wf1t  + (size_t)i * 4096 * 1024;
        const u16* wf2_i   = wf2t  + (size_t)i * 1024 * 4096;

        if ((i % G) == 0) {
            gemm_bt<E_BIAS_BF16, 1><<<G * 4096, 256, 0, stream>>>(
                bufC, wkvm + (size_t)i * 2048 * 1024, bufA,
                biaskv + i * 2048, nullptr, nullptr, 32768, kvN, 1024);
        }

        ln_k<true, true, false><<<2048, 256, 0, stream>>>(xres, lnl_g + i * 1024, lnl_b + i * 1024, latn);
        gemm64<E_BF16><<<32 * 24, 256, 0, stream>>>(latn, wqkvl_i, qkvl, nullptr, nullptr, 2048, 3072, 1024);
        attn_k<<<2048, 256, 0, stream>>>(qkvl, bufA + (size_t)(2 * (i % G)) * KV_PSLOT, obuf);
        gemm3232<E_ADD_F32><<<32 * 16, 256, 0, stream>>>(obuf, wot_i, xres, nullptr, xres, 2048, 1024, 1024);
        ln_k<true, true, false><<<2048, 256, 0, stream>>>(xres, ffn_g + i * 1024, ffn_b + i * 1024, ffny);
        gemm64<E_BIAS_GELU_BF16><<<32 * 32, 256, 0, stream>>>(ffny, wf1_i, ffnmid, ffb1 + i * 4096, nullptr, 2048, 4096, 1024);
        gemm3232<E_BIAS_ADD_F32><<<32 * 16, 256, 0, stream>>>(ffnmid, wf2_i, xres, ffb2 + i * 1024, xres, 2048, 1024, 4096);
    }

    // ---- final LN -> d_out (f32) ----
    ln_k<true, false, false><<<2048, 256, 0, stream>>>(xres, fin_g, fin_b, d_out);
}

// Round 17
// 2670.713 us; speedup vs baseline: 1.0168x; 1.0168x over previous
//
#include <hip/hip_runtime.h>
#include <math.h>

#define DEV __device__ __forceinline__

typedef __attribute__((ext_vector_type(8))) short short8;
typedef __attribute__((ext_vector_type(4))) short short4v;
typedef __attribute__((ext_vector_type(4))) float f32x4;
typedef __attribute__((ext_vector_type(8))) __bf16 bf16x8;

DEV float bf2f(unsigned short u) {
    union { unsigned int i; float f; } c; c.i = ((unsigned int)u) << 16; return c.f;
}
DEV unsigned short f2bf(float f) {
    union { float f; unsigned int i; } c; c.f = f;
    unsigned int u = c.i;
    u += 0x7fffu + ((u >> 16) & 1u);   // RNE
    return (unsigned short)(u >> 16);
}
DEV float gelu_exact(float x) { return 0.5f * x * (1.0f + erff(x * 0.70710678118654752f)); }

DEV f32x4 MF(bf16x8 a, bf16x8 b, f32x4 c) {
    return __builtin_amdgcn_mfma_f32_16x16x32_bf16(a, b, c, 0, 0, 0);
}

#define GLL16(g, l)                                                                   \
    __builtin_amdgcn_global_load_lds(                                                \
        (const __attribute__((address_space(1))) unsigned int*)(g),                  \
        (__attribute__((address_space(3))) unsigned int*)(l), 16, 0, 0)

// blocked-KV geometry: per (layer,part) slot = 128 bt x 16 h x 256 f x 64 d u16
#define KV_HSTR   16384ull                 // h stride (256*64)
#define KV_BTSTR  262144ull                // bt stride (16*16384)
#define KV_PSLOT  33554432ull              // (s*2+p) slot stride (128*262144)

// ---------------------------------------------------------------------------
// Weight transpose + f32->bf16 convert: in (K,N) f32 row-major -> out (N,K) bf16.
// ---------------------------------------------------------------------------
__global__ __launch_bounds__(256)
void transpose_w(const float* __restrict__ in, unsigned short* __restrict__ out,
                 const float* __restrict__ rowscale, float uscale,
                 int K, int N, size_t inStride, size_t outStride, int scaleStride)
{
    __shared__ float tile[64][65];
    in  += (size_t)blockIdx.z * inStride;
    out += (size_t)blockIdx.z * outStride;
    const int k0 = blockIdx.y * 64, n0 = blockIdx.x * 64;
    const int tid = threadIdx.x;
    const int c = tid & 63;
#pragma unroll
    for (int i = 0; i < 16; ++i) {
        int rr = (i << 2) + (tid >> 6);
        float v = in[(size_t)(k0 + rr) * N + n0 + c];
        if (rowscale) v *= rowscale[(size_t)blockIdx.z * scaleStride + k0 + rr];
        tile[rr][c] = v * uscale;
    }
    __syncthreads();
#pragma unroll
    for (int i = 0; i < 16; ++i) {
        int rr = (i << 2) + (tid >> 6);
        out[(size_t)(n0 + rr) * K + k0 + c] = f2bf(tile[c][rr]);
    }
}

// K-split partial: bpart[(blk48*8 + ks)*256 + tid] = sum over 128 rows
__global__ __launch_bounds__(256)
void fold_bias_part(const float* __restrict__ wk, const float* __restrict__ wv,
                    const float* __restrict__ bmed, float* __restrict__ bpart)
{
    const int d = blockIdx.x >> 3;
    const int rem = blockIdx.x & 7;
    const int part = rem >> 2;
    const int chunk = rem & 3;
    const int r0 = blockIdx.y * 128;
    const float* w = (part ? wv : wk) + (size_t)d * 1024 * 1024 + chunk * 256 + threadIdx.x;
    const float* b = bmed + d * 1024;
    float acc = 0.f;
    for (int r = r0; r < r0 + 128; ++r) acc += b[r] * w[(size_t)r * 1024];
    bpart[(size_t)(blockIdx.x * 8 + blockIdx.y) * 256 + threadIdx.x] = acc;
}

// deterministic reduce of the 8 k-slices
__global__ __launch_bounds__(256)
void fold_bias_red(const float* __restrict__ bpart, float* __restrict__ biaskv)
{
    const int d = blockIdx.x >> 3;
    const int rem = blockIdx.x & 7;
    const int part = rem >> 2;
    const int chunk = rem & 3;
    float acc = 0.f;
#pragma unroll
    for (int k = 0; k < 8; ++k)
        acc += bpart[(size_t)(blockIdx.x * 8 + k) * 256 + threadIdx.x];
    biaskv[d * 2048 + part * 1024 + chunk * 256 + threadIdx.x] = acc;
}

__global__ __launch_bounds__(256)
void convert_bf16(const float* __restrict__ in, unsigned short* __restrict__ out, size_t n4)
{
    size_t i = (size_t)blockIdx.x * 256 + threadIdx.x;
    if (i >= n4) return;
    float4 v = ((const float4*)in)[i];
    ushort4 u;
    u.x = f2bf(v.x); u.y = f2bf(v.y); u.z = f2bf(v.z); u.w = f2bf(v.w);
    ((ushort4*)out)[i] = u;
}

__global__ __launch_bounds__(256)
void init_x(const float* __restrict__ lat, float* __restrict__ x)
{
    const int row = blockIdx.x;
    ((float4*)x)[(size_t)row * 256 + threadIdx.x] =
        ((const float4*)lat)[(size_t)(row & 255) * 256 + threadIdx.x];
}

// ---------------------------------------------------------------------------
// LayerNorm over D=1024, one row per block. INBF: input is bf16 (u16).
// ---------------------------------------------------------------------------
template<bool AFFINE, bool OUTBF, bool INBF>
__global__ __launch_bounds__(256)
void ln_k(const void* __restrict__ in_, const float* __restrict__ g,
          const float* __restrict__ b, void* __restrict__ out)
{
    const int row = blockIdx.x;
    const int tid = threadIdx.x;
    float4 v;
    if (INBF) {
        ushort4 u = ((const ushort4*)((const unsigned short*)in_ + (size_t)row * 1024))[tid];
        v.x = bf2f(u.x); v.y = bf2f(u.y); v.z = bf2f(u.z); v.w = bf2f(u.w);
    } else {
        v = ((const float4*)((const float*)in_ + (size_t)row * 1024))[tid];
    }
    float s  = v.x + v.y + v.z + v.w;
    float ss = v.x * v.x + v.y * v.y + v.z * v.z + v.w * v.w;
#pragma unroll
    for (int o = 32; o > 0; o >>= 1) { s += __shfl_down(s, o); ss += __shfl_down(ss, o); }
    __shared__ float red[8];
    if ((tid & 63) == 0) { red[tid >> 6] = s; red[4 + (tid >> 6)] = ss; }
    __syncthreads();
    const float sum  = red[0] + red[1] + red[2] + red[3];
    const float ssum = red[4] + red[5] + red[6] + red[7];
    const float mean = sum * (1.0f / 1024.0f);
    const float var  = ssum * (1.0f / 1024.0f) - mean * mean;
    const float rs   = rsqrtf(var + 1e-5f);
    float o0 = (v.x - mean) * rs, o1 = (v.y - mean) * rs;
    float o2 = (v.z - mean) * rs, o3 = (v.w - mean) * rs;
    if (AFFINE) {
        float4 gv = ((const float4*)g)[tid];
        float4 bv = ((const float4*)b)[tid];
        o0 = o0 * gv.x + bv.x; o1 = o1 * gv.y + bv.y;
        o2 = o2 * gv.z + bv.z; o3 = o3 * gv.w + bv.w;
    }
    if (OUTBF) {
        ushort4 u; u.x = f2bf(o0); u.y = f2bf(o1); u.z = f2bf(o2); u.w = f2bf(o3);
        ((ushort4*)out)[(size_t)row * 256 + tid] = u;
    } else {
        float4 ov; ov.x = o0; ov.y = o1; ov.z = o2; ov.w = o3;
        ((float4*)out)[(size_t)row * 256 + tid] = ov;
    }
}

enum { E_BF16 = 0, E_BIAS_BF16, E_BIAS_GELU_BF16, E_BIAS_TPOS_BF16, E_ADD_F32, E_BIAS_ADD_F32 };

// ---------------------------------------------------------------------------
// Big-shape GEMM: 128x128 tile, BK=64, 4 waves, 32 KB LDS (~3 blocks/CU),
// global_load_lds with pre-swizzled source, conflict-free swizzled
// ds_read_b128 (cp = c ^ (row&7)), bijective XCD swizzle.
// MODE 0: flat output. MODE 1 ("grouped KV", measured 1.63x faster/layer):
// N = G*2048, grid = G*4096; per-XCD iteration s-group -> by -> bx keeps each
// group's B panel L2-resident. MODE-1 epilogue writes HEAD-BLOCKED layout
// [(s*2+p)*128+bt][h][f][d] so attention reads contiguous 32 KB tiles.
// C(M,N) = A(M,K) @ Bt(N,K)^T.
// ---------------------------------------------------------------------------
template<int EPI, int MODE>
__global__ __launch_bounds__(256, 2)
void gemm_bt(const unsigned short* __restrict__ A, const unsigned short* __restrict__ Bt,
             void* __restrict__ Out,
             const float* __restrict__ bias, const float* __restrict__ addsrc,
             const float* __restrict__ tpos,
             int M, int N, int K)
{
    __shared__ unsigned short lds[2 * 128 * 64];
    const int tid  = threadIdx.x;
    const int wave = tid >> 6, lane = tid & 63;
    const int nbx  = N >> 7;

    int by, bx;
    if (MODE == 1) {
        const int u = blockIdx.x >> 3;
        const int s = u >> 9;                  // depth group
        const int v = u & 511;
        by = (blockIdx.x & 7) * 32 + (v >> 4); // 0..255
        bx = s * 16 + (v & 15);
    } else {
        const int nwg = gridDim.x;
        int bid = blockIdx.x;
        int wg = ((nwg & 7) == 0) ? ((bid & 7) * (nwg >> 3) + (bid >> 3)) : bid;
        by = wg / nbx; bx = wg % nbx;
    }

    const int swz = ((lane & 7) ^ (lane >> 3)) * 8;
    const unsigned short* gA = A  + (size_t)(by * 128 + (lane >> 3)) * K + swz;
    const unsigned short* gB = Bt + (size_t)(bx * 128 + (lane >> 3)) * K + swz;

    const int wr = wave >> 1, wc = wave & 1;
    f32x4 acc[4][4] = {};

    unsigned short* ldsA = lds;
    unsigned short* ldsB = lds + 128 * 64;

    const int off0 = (((lane >> 4)    ) ^ (lane & 7)) * 8;
    const int off1 = (((lane >> 4) | 4) ^ (lane & 7)) * 8;
    const unsigned short* la = ldsA + (wr * 64 + (lane & 15)) * 64;
    const unsigned short* lb = ldsB + (wc * 64 + (lane & 15)) * 64;

    for (int kt = 0; kt < K; kt += 64) {
#pragma unroll
        for (int j = 0; j < 4; ++j) {
            const int chunk = (j << 2) + wave;   // wave-uniform
            GLL16(gA + (size_t)chunk * 8 * K + kt, ldsA + chunk * 512);
            GLL16(gB + (size_t)chunk * 8 * K + kt, ldsB + chunk * 512);
        }
        __syncthreads();
#pragma unroll
        for (int kk = 0; kk < 2; ++kk) {
            const int offk = kk ? off1 : off0;
            bf16x8 a[4], b[4];
#pragma unroll
            for (int m = 0; m < 4; ++m) a[m] = *(const bf16x8*)(la + m * 1024 + offk);
#pragma unroll
            for (int n = 0; n < 4; ++n) b[n] = *(const bf16x8*)(lb + n * 1024 + offk);
#pragma unroll
            for (int m = 0; m < 4; ++m)
#pragma unroll
                for (int n = 0; n < 4; ++n)
                    acc[m][n] = MF(a[m], b[n], acc[m][n]);
        }
        __syncthreads();
    }

    // epilogue: C/D layout col = lane&15, row = (lane>>4)*4 + reg  [m89-verified]
    const int r0 = by * 128 + wr * 64 + (lane >> 4) * 4;
    const int c0 = bx * 128 + wc * 64 + (lane & 15);
#pragma unroll
    for (int m = 0; m < 4; ++m) {
#pragma unroll
        for (int n = 0; n < 4; ++n) {
            const int c = c0 + n * 16;
            float bv = 0.f;
            if (EPI == E_BIAS_BF16 || EPI == E_BIAS_GELU_BF16 ||
                EPI == E_BIAS_TPOS_BF16 || EPI == E_BIAS_ADD_F32)
                bv = bias[c];
            // blocked-KV decomposition (MODE 1)
            const int s  = c >> 11;
            const int cx = c & 2047;
            const int p  = cx >> 10, hx = (cx >> 6) & 15, d = cx & 63;
#pragma unroll
            for (int j = 0; j < 4; ++j) {
                const int r = r0 + m * 16 + j;
                float v = acc[m][n][j] + bv;
                if (EPI == E_BIAS_GELU_BF16) v = gelu_exact(v);
                if (EPI == E_BIAS_TPOS_BF16) v += tpos[(((unsigned)r >> 8) & 15) * 1024 + c];
                if (EPI == E_ADD_F32 || EPI == E_BIAS_ADD_F32) v += addsrc[(size_t)r * N + c];
                if (MODE == 1) {
                    const int bt = r >> 8, f = r & 255;
                    ((unsigned short*)Out)[(size_t)((s * 2 + p) * 128 + bt) * KV_BTSTR +
                                           (size_t)hx * KV_HSTR + f * 64 + d] = f2bf(v);
                } else if (EPI == E_ADD_F32 || EPI == E_BIAS_ADD_F32) {
                    ((float*)Out)[(size_t)r * N + c] = v;
                } else {
                    ((unsigned short*)Out)[(size_t)r * N + c] = f2bf(v);
                }
            }
        }
    }
}

// ---------------------------------------------------------------------------
// Latent-stack GEMM: 64x128 tile, BK=64, 4 waves, 24 KB LDS, m97 skeleton +
// zero-conflict swizzle (r4-verified). Used for qkv (grid 768), ffn1 (1024).
// ---------------------------------------------------------------------------
template<int EPI>
__global__ __launch_bounds__(256, 4)
void gemm64(const unsigned short* __restrict__ A, const unsigned short* __restrict__ Bt,
            void* __restrict__ Out,
            const float* __restrict__ bias, const float* __restrict__ addsrc,
            int M, int N, int K)
{
    __shared__ unsigned short lds[64 * 64 + 128 * 64];
    const int tid  = threadIdx.x;
    const int wave = tid >> 6, lane = tid & 63;
    const int nbx  = N >> 7;

    const int nwg = gridDim.x;
    int bid = blockIdx.x;
    int wg = ((nwg & 7) == 0) ? ((bid & 7) * (nwg >> 3) + (bid >> 3)) : bid;
    const int by = wg / nbx, bx = wg % nbx;

    const int swz = ((lane & 7) ^ (lane >> 3)) * 8;
    const unsigned short* gA = A  + (size_t)(by * 64  + (lane >> 3)) * K + swz;
    const unsigned short* gB = Bt + (size_t)(bx * 128 + (lane >> 3)) * K + swz;

    const int wr = wave >> 1, wc = wave & 1;
    f32x4 acc[2][4] = {};

    unsigned short* ldsA = lds;
    unsigned short* ldsB = lds + 64 * 64;

    const int off0 = (((lane >> 4)    ) ^ (lane & 7)) * 8;
    const int off1 = (((lane >> 4) | 4) ^ (lane & 7)) * 8;
    const unsigned short* la = ldsA + (wr * 32 + (lane & 15)) * 64;
    const unsigned short* lb = ldsB + (wc * 64 + (lane & 15)) * 64;

    for (int kt = 0; kt < K; kt += 64) {
        GLL16(gA + (size_t)(wave)     * 8 * K + kt, ldsA + (wave)      * 512);
        GLL16(gA + (size_t)(4 + wave) * 8 * K + kt, ldsA + (4 + wave)  * 512);
#pragma unroll
        for (int j = 0; j < 4; ++j) {
            const int chunk = (j << 2) + wave;
            GLL16(gB + (size_t)chunk * 8 * K + kt, ldsB + chunk * 512);
        }
        __syncthreads();
#pragma unroll
        for (int kk = 0; kk < 2; ++kk) {
            const int offk = kk ? off1 : off0;
            bf16x8 a[2], b[4];
#pragma unroll
            for (int m = 0; m < 2; ++m) a[m] = *(const bf16x8*)(la + m * 1024 + offk);
#pragma unroll
            for (int n = 0; n < 4; ++n) b[n] = *(const bf16x8*)(lb + n * 1024 + offk);
#pragma unroll
            for (int m = 0; m < 2; ++m)
#pragma unroll
                for (int n = 0; n < 4; ++n)
                    acc[m][n] = MF(a[m], b[n], acc[m][n]);
        }
        __syncthreads();
    }

    const int r0 = by * 64 + wr * 32 + (lane >> 4) * 4;
    const int c0 = bx * 128 + wc * 64 + (lane & 15);
#pragma unroll
    for (int m = 0; m < 2; ++m) {
#pragma unroll
        for (int n = 0; n < 4; ++n) {
            const int c = c0 + n * 16;
#pragma unroll
            for (int j = 0; j < 4; ++j) {
                const int r = r0 + m * 16 + j;
                float v = acc[m][n][j];
                if (EPI == E_BIAS_BF16 || EPI == E_BIAS_GELU_BF16 || EPI == E_BIAS_ADD_F32)
                    v += bias[c];
                if (EPI == E_BIAS_GELU_BF16) v = gelu_exact(v);
                if (EPI == E_ADD_F32 || EPI == E_BIAS_ADD_F32) v += addsrc[(size_t)r * N + c];
                if (EPI == E_ADD_F32 || EPI == E_BIAS_ADD_F32)
                    ((float*)Out)[(size_t)r * N + c] = v;
                else
                    ((unsigned short*)Out)[(size_t)r * N + c] = f2bf(v);
            }
        }
    }
}

// ---------------------------------------------------------------------------
// Small-N GEMM: 64x64 tile, BK=64, 4 waves (wave-tile 32x32), 16 KB LDS ->
// 4 blocks/CU. For wo and ffn2 (N=1024): grid 512 (r9/r11 A/B-measured best).
// ---------------------------------------------------------------------------
template<int EPI>
__global__ __launch_bounds__(256, 4)
void gemm3232(const unsigned short* __restrict__ A, const unsigned short* __restrict__ Bt,
              void* __restrict__ Out,
              const float* __restrict__ bias, const float* __restrict__ addsrc,
              int M, int N, int K)
{
    __shared__ unsigned short lds[2 * 64 * 64];    // A then B, 16 KiB
    const int tid  = threadIdx.x;
    const int wave = tid >> 6, lane = tid & 63;
    const int nbx  = N >> 6;

    const int nwg = gridDim.x;
    int bid = blockIdx.x;
    int wg = ((nwg & 7) == 0) ? ((bid & 7) * (nwg >> 3) + (bid >> 3)) : bid;
    const int by = wg / nbx, bx = wg % nbx;

    const int swz = ((lane & 7) ^ (lane >> 3)) * 8;
    const unsigned short* gA = A  + (size_t)(by * 64 + (lane >> 3)) * K + swz;
    const unsigned short* gB = Bt + (size_t)(bx * 64 + (lane >> 3)) * K + swz;

    const int wr = wave >> 1, wc = wave & 1;
    f32x4 acc[2][2] = {};

    unsigned short* ldsA = lds;
    unsigned short* ldsB = lds + 64 * 64;

    const int off0 = (((lane >> 4)    ) ^ (lane & 7)) * 8;
    const int off1 = (((lane >> 4) | 4) ^ (lane & 7)) * 8;
    const unsigned short* la = ldsA + (wr * 32 + (lane & 15)) * 64;
    const unsigned short* lb = ldsB + (wc * 32 + (lane & 15)) * 64;

    for (int kt = 0; kt < K; kt += 64) {
        GLL16(gA + (size_t)(wave)     * 8 * K + kt, ldsA + (wave)      * 512);
        GLL16(gA + (size_t)(4 + wave) * 8 * K + kt, ldsA + (4 + wave)  * 512);
        GLL16(gB + (size_t)(wave)     * 8 * K + kt, ldsB + (wave)      * 512);
        GLL16(gB + (size_t)(4 + wave) * 8 * K + kt, ldsB + (4 + wave)  * 512);
        __syncthreads();
#pragma unroll
        for (int kk = 0; kk < 2; ++kk) {
            const int offk = kk ? off1 : off0;
            bf16x8 a[2], b[2];
#pragma unroll
            for (int m = 0; m < 2; ++m) a[m] = *(const bf16x8*)(la + m * 1024 + offk);
#pragma unroll
            for (int n = 0; n < 2; ++n) b[n] = *(const bf16x8*)(lb + n * 1024 + offk);
#pragma unroll
            for (int m = 0; m < 2; ++m)
#pragma unroll
                for (int n = 0; n < 2; ++n)
                    acc[m][n] = MF(a[m], b[n], acc[m][n]);
        }
        __syncthreads();
    }

    const int r0 = by * 64 + wr * 32 + (lane >> 4) * 4;
    const int c0 = bx * 64 + wc * 32 + (lane & 15);
#pragma unroll
    for (int m = 0; m < 2; ++m) {
#pragma unroll
        for (int n = 0; n < 2; ++n) {
            const int c = c0 + n * 16;
#pragma unroll
            for (int j = 0; j < 4; ++j) {
                const int r = r0 + m * 16 + j;
                float v = acc[m][n][j];
                if (EPI == E_BIAS_BF16 || EPI == E_BIAS_GELU_BF16 || EPI == E_BIAS_ADD_F32)
                    v += bias[c];
                if (EPI == E_BIAS_GELU_BF16) v = gelu_exact(v);
                if (EPI == E_ADD_F32 || EPI == E_BIAS_ADD_F32) v += addsrc[(size_t)r * N + c];
                if (EPI == E_ADD_F32 || EPI == E_BIAS_ADD_F32)
                    ((float*)Out)[(size_t)r * N + c] = v;
                else
                    ((unsigned short*)Out)[(size_t)r * N + c] = f2bf(v);
            }
        }
    }
}

// ---------------------------------------------------------------------------
// Attention (r15-measured best variant): one block per (bt, head).
// Q=16, F=272, DH=64. Media KV read from head-blocked layout: K tile =
// contiguous 32 KB at kbase + bt*KV_BTSTR + h*KV_HSTR; V = +KV_PSLOT.
// ---------------------------------------------------------------------------
__global__ __launch_bounds__(256)
void attn_k(const unsigned short* __restrict__ qkvl, const unsigned short* __restrict__ kbase,
            unsigned short* __restrict__ o)
{
    __shared__ unsigned short kv[272 * 72];
    __shared__ float sim[16 * 273];
    __shared__ float qs[16 * 68];
    __shared__ float red[64];

    const int bt = blockIdx.x >> 4, h = blockIdx.x & 15;
    const int tid = threadIdx.x;
    const int lane = tid & 63, wave = tid >> 6;
    const int r = tid & 15, grp = tid >> 4;

    const unsigned short* kt = kbase + (size_t)bt * KV_BTSTR + (size_t)h * KV_HSTR;

    {
        const int qi = tid >> 4, d0 = (tid & 15) * 4;
        const unsigned short* src = qkvl + (size_t)(bt * 16 + qi) * 3072 + h * 64 + d0;
        qs[qi * 68 + d0 + 0] = bf2f(src[0]);
        qs[qi * 68 + d0 + 1] = bf2f(src[1]);
        qs[qi * 68 + d0 + 2] = bf2f(src[2]);
        qs[qi * 68 + d0 + 3] = bf2f(src[3]);
    }
#pragma unroll
    for (int i = 0; i < 9; ++i) {
        int idx = i * 256 + tid;
        if (idx < 2176) {
            int f = idx >> 3, cp = idx & 7;
            const unsigned short* src = (f < 256)
                ? kt + f * 64 + cp * 8
                : qkvl + (size_t)(bt * 16 + (f - 256)) * 3072 + 1024 + h * 64 + cp * 8;
            *(short8*)&kv[f * 72 + cp * 8] = *(const short8*)src;
        }
    }
    __syncthreads();

    float p[17];
#pragma unroll
    for (int i = 0; i < 17; ++i) p[i] = 0.f;
#pragma unroll
    for (int d = 0; d < 64; d += 8) {
        float q8[8];
#pragma unroll
        for (int j = 0; j < 8; ++j) q8[j] = qs[r * 68 + d + j];
#pragma unroll
        for (int i = 0; i < 17; ++i) {
            short8 k8 = *(const short8*)&kv[(grp + i * 16) * 72 + d];
#pragma unroll
            for (int j = 0; j < 8; ++j) p[i] += q8[j] * bf2f((unsigned short)k8[j]);
        }
    }
    float mx = -3.0e38f;
#pragma unroll
    for (int i = 0; i < 17; ++i) mx = fmaxf(mx, p[i]);
    mx = fmaxf(mx, __shfl_xor(mx, 16));
    mx = fmaxf(mx, __shfl_xor(mx, 32));
    if (lane < 16) red[wave * 16 + lane] = mx;
    __syncthreads();
    const float rowmax = fmaxf(fmaxf(red[r], red[16 + r]), fmaxf(red[32 + r], red[48 + r]));

    float sm = 0.f;
#pragma unroll
    for (int i = 0; i < 17; ++i) { p[i] = __expf(p[i] - rowmax); sm += p[i]; }
    sm += __shfl_xor(sm, 16);
    sm += __shfl_xor(sm, 32);
#pragma unroll
    for (int i = 0; i < 17; ++i) sim[r * 273 + grp + i * 16] = p[i];
    __syncthreads();
    if (lane < 16) red[wave * 16 + lane] = sm;
#pragma unroll
    for (int i = 0; i < 9; ++i) {
        int idx = i * 256 + tid;
        if (idx < 2176) {
            int f = idx >> 3, cp = idx & 7;
            const unsigned short* src = (f < 256)
                ? kt + KV_PSLOT + f * 64 + cp * 8
                : qkvl + (size_t)(bt * 16 + (f - 256)) * 3072 + 2048 + h * 64 + cp * 8;
            *(short8*)&kv[f * 72 + cp * 8] = *(const short8*)src;
        }
    }
    __syncthreads();
    const float inv = 1.0f / (red[r] + red[16 + r] + red[32 + r] + red[48 + r]);

    float o0 = 0.f, o1 = 0.f, o2 = 0.f, o3 = 0.f;
    for (int f = 0; f < 272; ++f) {
        float pv = sim[r * 273 + f];
        short4v v4 = *(const short4v*)&kv[f * 72 + grp * 4];
        o0 += pv * bf2f((unsigned short)v4[0]);
        o1 += pv * bf2f((unsigned short)v4[1]);
        o2 += pv * bf2f((unsigned short)v4[2]);
        o3 += pv * bf2f((unsigned short)v4[3]);
    }
    unsigned short* dst = o + (size_t)(bt * 16 + r) * 1024 + h * 64 + grp * 4;
    dst[0] = f2bf(o0 * inv);
    dst[1] = f2bf(o1 * inv);
    dst[2] = f2bf(o2 * inv);
    dst[3] = f2bf(o3 * inv);
}

// ---------------------------------------------------------------------------
extern "C" void kernel_launch(void* const* d_in, const int* in_sizes, int n_in,
                              void* d_out, int out_size, void* d_ws, size_t ws_size,
                              hipStream_t stream)
{
    const float* x_f      = (const float*)d_in[0];
    const float* goal_w1  = (const float*)d_in[1];
    const float* goal_b1  = (const float*)d_in[2];
    const float* goal_w2  = (const float*)d_in[3];
    const float* goal_b2  = (const float*)d_in[4];
    const float* latents  = (const float*)d_in[5];
    const float* tpos     = (const float*)d_in[6];
    const float* lnm_g    = (const float*)d_in[7];
    const float* lnm_b    = (const float*)d_in[8];
    const float* lnl_g    = (const float*)d_in[9];
    const float* lnl_b    = (const float*)d_in[10];
    const float* wq       = (const float*)d_in[11];
    const float* wk       = (const float*)d_in[12];
    const float* wv       = (const float*)d_in[13];
    const float* wo       = (const float*)d_in[14];
    const float* ffn_g    = (const float*)d_in[15];
    const float* ffn_b    = (const float*)d_in[16];
    const float* ffw1     = (const float*)d_in[17];
    const float* ffb1     = (const float*)d_in[18];
    const float* ffw2     = (const float*)d_in[19];
    const float* ffb2     = (const float*)d_in[20];
    const float* fin_g    = (const float*)d_in[21];
    const float* fin_b    = (const float*)d_in[22];

    char* ws = (char*)d_ws;
    size_t off = 0;
    auto alloc = [&](size_t bytes) -> char* {
        char* p = ws + off;
        off += (bytes + 255) & ~(size_t)255;
        return p;
    };
    typedef unsigned short u16;
    u16*   wg1t   = (u16*)  alloc(2048ull * 1280 * 2);
    u16*   wg2t   = (u16*)  alloc(1024ull * 2048 * 2);
    u16*   wqkvl  = (u16*)  alloc(6ull * 3072 * 1024 * 2);
    u16*   wkvm   = (u16*)  alloc(6ull * 2048 * 1024 * 2);
    u16*   wot    = (u16*)  alloc(6ull * 1024 * 1024 * 2);
    u16*   wf1t   = (u16*)  alloc(6ull * 4096 * 1024 * 2);
    u16*   wf2t   = (u16*)  alloc(6ull * 1024 * 4096 * 2);
    float* biaskv = (float*)alloc(6ull * 2048 * 4);
    float* bpart  = (float*)alloc(384ull * 256 * 4);
    float* xres   = (float*)alloc(2048ull * 1024 * 4);
    u16*   latn   = (u16*)  alloc(2048ull * 1024 * 2);
    u16*   qkvl   = (u16*)  alloc(2048ull * 3072 * 2);
    u16*   obuf   = (u16*)  alloc(2048ull * 1024 * 2);
    u16*   ffny   = (u16*)  alloc(2048ull * 1024 * 2);
    u16*   ffnmid = (u16*)  alloc(2048ull * 4096 * 2);
    u16*   bufB   = (u16*)  alloc(32768ull * 1024 * 2);   // goal output, bf16
    u16*   bufC   = (u16*)  alloc(41943040ull * 2);       // x_f bf16, then nf
    if (off > ws_size) return;
    // bufA last: grouped-KV buffer. Pick largest G in {6,3,2,1} that fits.
    const size_t singleBytes = 32768ull * 2048 * 2;       // per-layer KV = 134 MB
    int G = 1;
    if (off + 6 * singleBytes <= ws_size)      G = 6;
    else if (off + 3 * singleBytes <= ws_size) G = 3;
    else if (off + 2 * singleBytes <= ws_size) G = 2;
    u16* bufA = (u16*)alloc((size_t)G * singleBytes);
    if (off > ws_size) return;
    const int kvN = G * 2048;

    // ---- phase 0: conversions / folds ----
    convert_bf16<<<40960, 256, 0, stream>>>(x_f, bufC, 41943040ull / 4);
    transpose_w<<<dim3(32, 20, 1), 256, 0, stream>>>(goal_w1, wg1t, nullptr, 1.f, 1280, 2048, 0, 0, 0);
    transpose_w<<<dim3(16, 32, 1), 256, 0, stream>>>(goal_w2, wg2t, nullptr, 1.f, 2048, 1024, 0, 0, 0);
    transpose_w<<<dim3(16, 16, 6), 256, 0, stream>>>(wq, wqkvl,                nullptr, 0.125f, 1024, 1024, 1024ull*1024, 3072ull*1024, 0);
    transpose_w<<<dim3(16, 16, 6), 256, 0, stream>>>(wk, wqkvl + 1024ull*1024, nullptr, 1.f,    1024, 1024, 1024ull*1024, 3072ull*1024, 0);
    transpose_w<<<dim3(16, 16, 6), 256, 0, stream>>>(wv, wqkvl + 2048ull*1024, nullptr, 1.f,    1024, 1024, 1024ull*1024, 3072ull*1024, 0);
    transpose_w<<<dim3(16, 16, 6), 256, 0, stream>>>(wk, wkvm,                 lnm_g,   1.f,    1024, 1024, 1024ull*1024, 2048ull*1024, 1024);
    transpose_w<<<dim3(16, 16, 6), 256, 0, stream>>>(wv, wkvm + 1024ull*1024,  lnm_g,   1.f,    1024, 1024, 1024ull*1024, 2048ull*1024, 1024);
    transpose_w<<<dim3(16, 16, 6), 256, 0, stream>>>(wo, wot,                  nullptr, 1.f,    1024, 1024, 1024ull*1024, 1024ull*1024, 0);
    transpose_w<<<dim3(64, 16, 6), 256, 0, stream>>>(ffw1, wf1t,               nullptr, 1.f,    1024, 4096, 4096ull*1024, 4096ull*1024, 0);
    transpose_w<<<dim3(16, 64, 6), 256, 0, stream>>>(ffw2, wf2t,               nullptr, 1.f,    4096, 1024, 4096ull*1024, 4096ull*1024, 0);
    fold_bias_part<<<dim3(48, 8), 256, 0, stream>>>(wk, wv, lnm_b, bpart);
    fold_bias_red<<<48, 256, 0, stream>>>(bpart, biaskv);
    init_x<<<2048, 256, 0, stream>>>(latents, xres);

    // ---- goal MLP ----
    gemm_bt<E_BIAS_GELU_BF16, 0><<<256 * 16, 256, 0, stream>>>(bufC, wg1t, bufA, goal_b1, nullptr, nullptr, 32768, 2048, 1280);
    gemm_bt<E_BIAS_TPOS_BF16, 0><<<256 * 8, 256, 0, stream>>>(bufA, wg2t, bufB, goal_b2, nullptr, tpos, 32768, 1024, 2048);
    ln_k<false, true, true><<<32768, 256, 0, stream>>>(bufB, nullptr, nullptr, bufC);   // nf

    // ---- depth loop (grouped KV: one merged GEMM per G layers, blocked layout) ----
    for (int i = 0; i < 6; ++i) {
        const u16* wqkvl_i = wqkvl + (size_t)i * 3072 * 1024;
        const u16* wot_i   = wot   + (size_t)i * 1024 * 1024;
        const u16* wf1_i   = wf1t  + (size_t)i * 4096 * 1024;
        const u16* wf2_i   = wf2t  + (size_t)i * 1024 * 4096;

        if ((i % G) == 0) {
            gemm_bt<E_BIAS_BF16, 1><<<G * 4096, 256, 0, stream>>>(
                bufC, wkvm + (size_t)i * 2048 * 1024, bufA,
                biaskv + i * 2048, nullptr, nullptr, 32768, kvN, 1024);
        }

        ln_k<true, true, false><<<2048, 256, 0, stream>>>(xres, lnl_g + i * 1024, lnl_b + i * 1024, latn);
        gemm64<E_BF16><<<32 * 24, 256, 0, stream>>>(latn, wqkvl_i, qkvl, nullptr, nullptr, 2048, 3072, 1024);
        attn_k<<<2048, 256, 0, stream>>>(qkvl, bufA + (size_t)(2 * (i % G)) * KV_PSLOT, obuf);
        gemm3232<E_ADD_F32><<<32 * 16, 256, 0, stream>>>(obuf, wot_i, xres, nullptr, xres, 2048, 1024, 1024);
        ln_k<true, true, false><<<2048, 256, 0, stream>>>(xres, ffn_g + i * 1024, ffn_b + i * 1024, ffny);
        gemm64<E_BIAS_GELU_BF16><<<32 * 32, 256, 0, stream>>>(ffny, wf1_i, ffnmid, ffb1 + i * 4096, nullptr, 2048, 4096, 1024);
        gemm3232<E_BIAS_ADD_F32><<<32 * 16, 256, 0, stream>>>(ffnmid, wf2_i, xres, ffb2 + i * 1024, xres, 2048, 1024, 4096);
    }

    // ---- final LN -> d_out (f32) ----
    ln_k<true, false, false><<<2048, 256, 0, stream>>>(xres, fin_g, fin_b, d_out);
}

// Round 18
// 2639.617 us; speedup vs baseline: 1.0287x; 1.0118x over previous
//
#include <hip/hip_runtime.h>
#include <math.h>

#define DEV __device__ __forceinline__

typedef __attribute__((ext_vector_type(8))) short short8;
typedef __attribute__((ext_vector_type(4))) short short4v;
typedef __attribute__((ext_vector_type(4))) float f32x4;
typedef __attribute__((ext_vector_type(8))) __bf16 bf16x8;

DEV float bf2f(unsigned short u) {
    union { unsigned int i; float f; } c; c.i = ((unsigned int)u) << 16; return c.f;
}
DEV unsigned short f2bf(float f) {
    union { float f; unsigned int i; } c; c.f = f;
    unsigned int u = c.i;
    u += 0x7fffu + ((u >> 16) & 1u);   // RNE
    return (unsigned short)(u >> 16);
}
DEV float gelu_exact(float x) { return 0.5f * x * (1.0f + erff(x * 0.70710678118654752f)); }

DEV f32x4 MF(bf16x8 a, bf16x8 b, f32x4 c) {
    return __builtin_amdgcn_mfma_f32_16x16x32_bf16(a, b, c, 0, 0, 0);
}

#define GLL16(g, l)                                                                   \
    __builtin_amdgcn_global_load_lds(                                                \
        (const __attribute__((address_space(1))) unsigned int*)(g),                  \
        (__attribute__((address_space(3))) unsigned int*)(l), 16, 0, 0)

// lgkm-only barrier (m201 pattern): drains DS ops but leaves global loads
// in flight across the barrier (T14 async-stage prerequisite).
#define BARL() do { asm volatile("s_waitcnt lgkmcnt(0)" ::: "memory");                \
                    __builtin_amdgcn_s_barrier(); } while (0)

// blocked-KV geometry: per (layer,part) slot = 128 bt x 16 h x 256 f x 64 d u16
#define KV_HSTR   16384ull                 // h stride (256*64)
#define KV_BTSTR  262144ull                // bt stride (16*16384)
#define KV_PSLOT  33554432ull              // (s*2+p) slot stride (128*262144)

// ---------------------------------------------------------------------------
// Weight transpose + f32->bf16 convert: in (K,N) f32 row-major -> out (N,K) bf16.
// ---------------------------------------------------------------------------
__global__ __launch_bounds__(256)
void transpose_w(const float* __restrict__ in, unsigned short* __restrict__ out,
                 const float* __restrict__ rowscale, float uscale,
                 int K, int N, size_t inStride, size_t outStride, int scaleStride)
{
    __shared__ float tile[64][65];
    in  += (size_t)blockIdx.z * inStride;
    out += (size_t)blockIdx.z * outStride;
    const int k0 = blockIdx.y * 64, n0 = blockIdx.x * 64;
    const int tid = threadIdx.x;
    const int c = tid & 63;
#pragma unroll
    for (int i = 0; i < 16; ++i) {
        int rr = (i << 2) + (tid >> 6);
        float v = in[(size_t)(k0 + rr) * N + n0 + c];
        if (rowscale) v *= rowscale[(size_t)blockIdx.z * scaleStride + k0 + rr];
        tile[rr][c] = v * uscale;
    }
    __syncthreads();
#pragma unroll
    for (int i = 0; i < 16; ++i) {
        int rr = (i << 2) + (tid >> 6);
        out[(size_t)(n0 + rr) * K + k0 + c] = f2bf(tile[c][rr]);
    }
}

// K-split partial: bpart[(blk48*8 + ks)*256 + tid] = sum over 128 rows
__global__ __launch_bounds__(256)
void fold_bias_part(const float* __restrict__ wk, const float* __restrict__ wv,
                    const float* __restrict__ bmed, float* __restrict__ bpart)
{
    const int d = blockIdx.x >> 3;
    const int rem = blockIdx.x & 7;
    const int part = rem >> 2;
    const int chunk = rem & 3;
    const int r0 = blockIdx.y * 128;
    const float* w = (part ? wv : wk) + (size_t)d * 1024 * 1024 + chunk * 256 + threadIdx.x;
    const float* b = bmed + d * 1024;
    float acc = 0.f;
    for (int r = r0; r < r0 + 128; ++r) acc += b[r] * w[(size_t)r * 1024];
    bpart[(size_t)(blockIdx.x * 8 + blockIdx.y) * 256 + threadIdx.x] = acc;
}

// deterministic reduce of the 8 k-slices
__global__ __launch_bounds__(256)
void fold_bias_red(const float* __restrict__ bpart, float* __restrict__ biaskv)
{
    const int d = blockIdx.x >> 3;
    const int rem = blockIdx.x & 7;
    const int part = rem >> 2;
    const int chunk = rem & 3;
    float acc = 0.f;
#pragma unroll
    for (int k = 0; k < 8; ++k)
        acc += bpart[(size_t)(blockIdx.x * 8 + k) * 256 + threadIdx.x];
    biaskv[d * 2048 + part * 1024 + chunk * 256 + threadIdx.x] = acc;
}

__global__ __launch_bounds__(256)
void convert_bf16(const float* __restrict__ in, unsigned short* __restrict__ out, size_t n4)
{
    size_t i = (size_t)blockIdx.x * 256 + threadIdx.x;
    if (i >= n4) return;
    float4 v = ((const float4*)in)[i];
    ushort4 u;
    u.x = f2bf(v.x); u.y = f2bf(v.y); u.z = f2bf(v.z); u.w = f2bf(v.w);
    ((ushort4*)out)[i] = u;
}

__global__ __launch_bounds__(256)
void init_x(const float* __restrict__ lat, float* __restrict__ x)
{
    const int row = blockIdx.x;
    ((float4*)x)[(size_t)row * 256 + threadIdx.x] =
        ((const float4*)lat)[(size_t)(row & 255) * 256 + threadIdx.x];
}

// ---------------------------------------------------------------------------
// LayerNorm over D=1024, one row per block. INBF: input is bf16 (u16).
// ---------------------------------------------------------------------------
template<bool AFFINE, bool OUTBF, bool INBF>
__global__ __launch_bounds__(256)
void ln_k(const void* __restrict__ in_, const float* __restrict__ g,
          const float* __restrict__ b, void* __restrict__ out)
{
    const int row = blockIdx.x;
    const int tid = threadIdx.x;
    float4 v;
    if (INBF) {
        ushort4 u = ((const ushort4*)((const unsigned short*)in_ + (size_t)row * 1024))[tid];
        v.x = bf2f(u.x); v.y = bf2f(u.y); v.z = bf2f(u.z); v.w = bf2f(u.w);
    } else {
        v = ((const float4*)((const float*)in_ + (size_t)row * 1024))[tid];
    }
    float s  = v.x + v.y + v.z + v.w;
    float ss = v.x * v.x + v.y * v.y + v.z * v.z + v.w * v.w;
#pragma unroll
    for (int o = 32; o > 0; o >>= 1) { s += __shfl_down(s, o); ss += __shfl_down(ss, o); }
    __shared__ float red[8];
    if ((tid & 63) == 0) { red[tid >> 6] = s; red[4 + (tid >> 6)] = ss; }
    __syncthreads();
    const float sum  = red[0] + red[1] + red[2] + red[3];
    const float ssum = red[4] + red[5] + red[6] + red[7];
    const float mean = sum * (1.0f / 1024.0f);
    const float var  = ssum * (1.0f / 1024.0f) - mean * mean;
    const float rs   = rsqrtf(var + 1e-5f);
    float o0 = (v.x - mean) * rs, o1 = (v.y - mean) * rs;
    float o2 = (v.z - mean) * rs, o3 = (v.w - mean) * rs;
    if (AFFINE) {
        float4 gv = ((const float4*)g)[tid];
        float4 bv = ((const float4*)b)[tid];
        o0 = o0 * gv.x + bv.x; o1 = o1 * gv.y + bv.y;
        o2 = o2 * gv.z + bv.z; o3 = o3 * gv.w + bv.w;
    }
    if (OUTBF) {
        ushort4 u; u.x = f2bf(o0); u.y = f2bf(o1); u.z = f2bf(o2); u.w = f2bf(o3);
        ((ushort4*)out)[(size_t)row * 256 + tid] = u;
    } else {
        float4 ov; ov.x = o0; ov.y = o1; ov.z = o2; ov.w = o3;
        ((float4*)out)[(size_t)row * 256 + tid] = ov;
    }
}

enum { E_BF16 = 0, E_BIAS_BF16, E_BIAS_GELU_BF16, E_BIAS_TPOS_BF16, E_ADD_F32, E_BIAS_ADD_F32 };

// ---------------------------------------------------------------------------
// Big-shape GEMM: 128x128 tile, BK=64, 4 waves, 32 KB LDS (~3 blocks/CU),
// global_load_lds with pre-swizzled source, conflict-free swizzled
// ds_read_b128 (cp = c ^ (row&7)), bijective XCD swizzle.
// MODE 0: flat output. MODE 1 ("grouped KV", measured 1.63x faster/layer):
// N = G*2048, grid = G*4096; per-XCD iteration s-group -> by -> bx keeps each
// group's B panel L2-resident. MODE-1 epilogue writes HEAD-BLOCKED layout
// [(s*2+p)*128+bt][h][f][d] so attention reads contiguous 32 KB tiles.
// C(M,N) = A(M,K) @ Bt(N,K)^T.
// ---------------------------------------------------------------------------
template<int EPI, int MODE>
__global__ __launch_bounds__(256, 2)
void gemm_bt(const unsigned short* __restrict__ A, const unsigned short* __restrict__ Bt,
             void* __restrict__ Out,
             const float* __restrict__ bias, const float* __restrict__ addsrc,
             const float* __restrict__ tpos,
             int M, int N, int K)
{
    __shared__ unsigned short lds[2 * 128 * 64];
    const int tid  = threadIdx.x;
    const int wave = tid >> 6, lane = tid & 63;
    const int nbx  = N >> 7;

    int by, bx;
    if (MODE == 1) {
        const int u = blockIdx.x >> 3;
        const int s = u >> 9;                  // depth group
        const int v = u & 511;
        by = (blockIdx.x & 7) * 32 + (v >> 4); // 0..255
        bx = s * 16 + (v & 15);
    } else {
        const int nwg = gridDim.x;
        int bid = blockIdx.x;
        int wg = ((nwg & 7) == 0) ? ((bid & 7) * (nwg >> 3) + (bid >> 3)) : bid;
        by = wg / nbx; bx = wg % nbx;
    }

    const int swz = ((lane & 7) ^ (lane >> 3)) * 8;
    const unsigned short* gA = A  + (size_t)(by * 128 + (lane >> 3)) * K + swz;
    const unsigned short* gB = Bt + (size_t)(bx * 128 + (lane >> 3)) * K + swz;

    const int wr = wave >> 1, wc = wave & 1;
    f32x4 acc[4][4] = {};

    unsigned short* ldsA = lds;
    unsigned short* ldsB = lds + 128 * 64;

    const int off0 = (((lane >> 4)    ) ^ (lane & 7)) * 8;
    const int off1 = (((lane >> 4) | 4) ^ (lane & 7)) * 8;
    const unsigned short* la = ldsA + (wr * 64 + (lane & 15)) * 64;
    const unsigned short* lb = ldsB + (wc * 64 + (lane & 15)) * 64;

    for (int kt = 0; kt < K; kt += 64) {
#pragma unroll
        for (int j = 0; j < 4; ++j) {
            const int chunk = (j << 2) + wave;   // wave-uniform
            GLL16(gA + (size_t)chunk * 8 * K + kt, ldsA + chunk * 512);
            GLL16(gB + (size_t)chunk * 8 * K + kt, ldsB + chunk * 512);
        }
        __syncthreads();
#pragma unroll
        for (int kk = 0; kk < 2; ++kk) {
            const int offk = kk ? off1 : off0;
            bf16x8 a[4], b[4];
#pragma unroll
            for (int m = 0; m < 4; ++m) a[m] = *(const bf16x8*)(la + m * 1024 + offk);
#pragma unroll
            for (int n = 0; n < 4; ++n) b[n] = *(const bf16x8*)(lb + n * 1024 + offk);
#pragma unroll
            for (int m = 0; m < 4; ++m)
#pragma unroll
                for (int n = 0; n < 4; ++n)
                    acc[m][n] = MF(a[m], b[n], acc[m][n]);
        }
        __syncthreads();
    }

    // epilogue: C/D layout col = lane&15, row = (lane>>4)*4 + reg  [m89-verified]
    const int r0 = by * 128 + wr * 64 + (lane >> 4) * 4;
    const int c0 = bx * 128 + wc * 64 + (lane & 15);
#pragma unroll
    for (int m = 0; m < 4; ++m) {
#pragma unroll
        for (int n = 0; n < 4; ++n) {
            const int c = c0 + n * 16;
            float bv = 0.f;
            if (EPI == E_BIAS_BF16 || EPI == E_BIAS_GELU_BF16 ||
                EPI == E_BIAS_TPOS_BF16 || EPI == E_BIAS_ADD_F32)
                bv = bias[c];
            // blocked-KV decomposition (MODE 1)
            const int s  = c >> 11;
            const int cx = c & 2047;
            const int p  = cx >> 10, hx = (cx >> 6) & 15, d = cx & 63;
#pragma unroll
            for (int j = 0; j < 4; ++j) {
                const int r = r0 + m * 16 + j;
                float v = acc[m][n][j] + bv;
                if (EPI == E_BIAS_GELU_BF16) v = gelu_exact(v);
                if (EPI == E_BIAS_TPOS_BF16) v += tpos[(((unsigned)r >> 8) & 15) * 1024 + c];
                if (EPI == E_ADD_F32 || EPI == E_BIAS_ADD_F32) v += addsrc[(size_t)r * N + c];
                if (MODE == 1) {
                    const int bt = r >> 8, f = r & 255;
                    ((unsigned short*)Out)[(size_t)((s * 2 + p) * 128 + bt) * KV_BTSTR +
                                           (size_t)hx * KV_HSTR + f * 64 + d] = f2bf(v);
                } else if (EPI == E_ADD_F32 || EPI == E_BIAS_ADD_F32) {
                    ((float*)Out)[(size_t)r * N + c] = v;
                } else {
                    ((unsigned short*)Out)[(size_t)r * N + c] = f2bf(v);
                }
            }
        }
    }
}

// ---------------------------------------------------------------------------
// Latent-stack GEMM: 64x128 tile, BK=64, 4 waves, 24 KB LDS, m97 skeleton +
// zero-conflict swizzle (r4-verified). Used for qkv (grid 768), ffn1 (1024).
// ---------------------------------------------------------------------------
template<int EPI>
__global__ __launch_bounds__(256, 4)
void gemm64(const unsigned short* __restrict__ A, const unsigned short* __restrict__ Bt,
            void* __restrict__ Out,
            const float* __restrict__ bias, const float* __restrict__ addsrc,
            int M, int N, int K)
{
    __shared__ unsigned short lds[64 * 64 + 128 * 64];
    const int tid  = threadIdx.x;
    const int wave = tid >> 6, lane = tid & 63;
    const int nbx  = N >> 7;

    const int nwg = gridDim.x;
    int bid = blockIdx.x;
    int wg = ((nwg & 7) == 0) ? ((bid & 7) * (nwg >> 3) + (bid >> 3)) : bid;
    const int by = wg / nbx, bx = wg % nbx;

    const int swz = ((lane & 7) ^ (lane >> 3)) * 8;
    const unsigned short* gA = A  + (size_t)(by * 64  + (lane >> 3)) * K + swz;
    const unsigned short* gB = Bt + (size_t)(bx * 128 + (lane >> 3)) * K + swz;

    const int wr = wave >> 1, wc = wave & 1;
    f32x4 acc[2][4] = {};

    unsigned short* ldsA = lds;
    unsigned short* ldsB = lds + 64 * 64;

    const int off0 = (((lane >> 4)    ) ^ (lane & 7)) * 8;
    const int off1 = (((lane >> 4) | 4) ^ (lane & 7)) * 8;
    const unsigned short* la = ldsA + (wr * 32 + (lane & 15)) * 64;
    const unsigned short* lb = ldsB + (wc * 64 + (lane & 15)) * 64;

    for (int kt = 0; kt < K; kt += 64) {
        GLL16(gA + (size_t)(wave)     * 8 * K + kt, ldsA + (wave)      * 512);
        GLL16(gA + (size_t)(4 + wave) * 8 * K + kt, ldsA + (4 + wave)  * 512);
#pragma unroll
        for (int j = 0; j < 4; ++j) {
            const int chunk = (j << 2) + wave;
            GLL16(gB + (size_t)chunk * 8 * K + kt, ldsB + chunk * 512);
        }
        __syncthreads();
#pragma unroll
        for (int kk = 0; kk < 2; ++kk) {
            const int offk = kk ? off1 : off0;
            bf16x8 a[2], b[4];
#pragma unroll
            for (int m = 0; m < 2; ++m) a[m] = *(const bf16x8*)(la + m * 1024 + offk);
#pragma unroll
            for (int n = 0; n < 4; ++n) b[n] = *(const bf16x8*)(lb + n * 1024 + offk);
#pragma unroll
            for (int m = 0; m < 2; ++m)
#pragma unroll
                for (int n = 0; n < 4; ++n)
                    acc[m][n] = MF(a[m], b[n], acc[m][n]);
        }
        __syncthreads();
    }

    const int r0 = by * 64 + wr * 32 + (lane >> 4) * 4;
    const int c0 = bx * 128 + wc * 64 + (lane & 15);
#pragma unroll
    for (int m = 0; m < 2; ++m) {
#pragma unroll
        for (int n = 0; n < 4; ++n) {
            const int c = c0 + n * 16;
#pragma unroll
            for (int j = 0; j < 4; ++j) {
                const int r = r0 + m * 16 + j;
                float v = acc[m][n][j];
                if (EPI == E_BIAS_BF16 || EPI == E_BIAS_GELU_BF16 || EPI == E_BIAS_ADD_F32)
                    v += bias[c];
                if (EPI == E_BIAS_GELU_BF16) v = gelu_exact(v);
                if (EPI == E_ADD_F32 || EPI == E_BIAS_ADD_F32) v += addsrc[(size_t)r * N + c];
                if (EPI == E_ADD_F32 || EPI == E_BIAS_ADD_F32)
                    ((float*)Out)[(size_t)r * N + c] = v;
                else
                    ((unsigned short*)Out)[(size_t)r * N + c] = f2bf(v);
            }
        }
    }
}

// ---------------------------------------------------------------------------
// Small-N GEMM: 64x64 tile, BK=64, 4 waves (wave-tile 32x32), 16 KB LDS ->
// 4 blocks/CU. For wo and ffn2 (N=1024): grid 512 (r9/r11 A/B-measured best).
// ---------------------------------------------------------------------------
template<int EPI>
__global__ __launch_bounds__(256, 4)
void gemm3232(const unsigned short* __restrict__ A, const unsigned short* __restrict__ Bt,
              void* __restrict__ Out,
              const float* __restrict__ bias, const float* __restrict__ addsrc,
              int M, int N, int K)
{
    __shared__ unsigned short lds[2 * 64 * 64];    // A then B, 16 KiB
    const int tid  = threadIdx.x;
    const int wave = tid >> 6, lane = tid & 63;
    const int nbx  = N >> 6;

    const int nwg = gridDim.x;
    int bid = blockIdx.x;
    int wg = ((nwg & 7) == 0) ? ((bid & 7) * (nwg >> 3) + (bid >> 3)) : bid;
    const int by = wg / nbx, bx = wg % nbx;

    const int swz = ((lane & 7) ^ (lane >> 3)) * 8;
    const unsigned short* gA = A  + (size_t)(by * 64 + (lane >> 3)) * K + swz;
    const unsigned short* gB = Bt + (size_t)(bx * 64 + (lane >> 3)) * K + swz;

    const int wr = wave >> 1, wc = wave & 1;
    f32x4 acc[2][2] = {};

    unsigned short* ldsA = lds;
    unsigned short* ldsB = lds + 64 * 64;

    const int off0 = (((lane >> 4)    ) ^ (lane & 7)) * 8;
    const int off1 = (((lane >> 4) | 4) ^ (lane & 7)) * 8;
    const unsigned short* la = ldsA + (wr * 32 + (lane & 15)) * 64;
    const unsigned short* lb = ldsB + (wc * 32 + (lane & 15)) * 64;

    for (int kt = 0; kt < K; kt += 64) {
        GLL16(gA + (size_t)(wave)     * 8 * K + kt, ldsA + (wave)      * 512);
        GLL16(gA + (size_t)(4 + wave) * 8 * K + kt, ldsA + (4 + wave)  * 512);
        GLL16(gB + (size_t)(wave)     * 8 * K + kt, ldsB + (wave)      * 512);
        GLL16(gB + (size_t)(4 + wave) * 8 * K + kt, ldsB + (4 + wave)  * 512);
        __syncthreads();
#pragma unroll
        for (int kk = 0; kk < 2; ++kk) {
            const int offk = kk ? off1 : off0;
            bf16x8 a[2], b[2];
#pragma unroll
            for (int m = 0; m < 2; ++m) a[m] = *(const bf16x8*)(la + m * 1024 + offk);
#pragma unroll
            for (int n = 0; n < 2; ++n) b[n] = *(const bf16x8*)(lb + n * 1024 + offk);
#pragma unroll
            for (int m = 0; m < 2; ++m)
#pragma unroll
                for (int n = 0; n < 2; ++n)
                    acc[m][n] = MF(a[m], b[n], acc[m][n]);
        }
        __syncthreads();
    }

    const int r0 = by * 64 + wr * 32 + (lane >> 4) * 4;
    const int c0 = bx * 64 + wc * 32 + (lane & 15);
#pragma unroll
    for (int m = 0; m < 2; ++m) {
#pragma unroll
        for (int n = 0; n < 2; ++n) {
            const int c = c0 + n * 16;
#pragma unroll
            for (int j = 0; j < 4; ++j) {
                const int r = r0 + m * 16 + j;
                float v = acc[m][n][j];
                if (EPI == E_BIAS_BF16 || EPI == E_BIAS_GELU_BF16 || EPI == E_BIAS_ADD_F32)
                    v += bias[c];
                if (EPI == E_BIAS_GELU_BF16) v = gelu_exact(v);
                if (EPI == E_ADD_F32 || EPI == E_BIAS_ADD_F32) v += addsrc[(size_t)r * N + c];
                if (EPI == E_ADD_F32 || EPI == E_BIAS_ADD_F32)
                    ((float*)Out)[(size_t)r * N + c] = v;
                else
                    ((unsigned short*)Out)[(size_t)r * N + c] = f2bf(v);
            }
        }
    }
}

// ---------------------------------------------------------------------------
// Attention v3 (T14 async-V): one block per (bt, head). Q=16, F=272, DH=64.
// V-tile global loads issue into registers right after the K-stage issues;
// lgkm-only barriers (BARL) keep them in flight across QK^T+softmax; the
// post-softmax V phase is pure ds_writes from registers (compiler inserts
// the counted vmcnt waits on the vreg data deps). Arithmetic identical to
// the r15/r17 kernel. Media KV read from head-blocked layout.
// ---------------------------------------------------------------------------
__global__ __launch_bounds__(256)
void attn_k(const unsigned short* __restrict__ qkvl, const unsigned short* __restrict__ kbase,
            unsigned short* __restrict__ o)
{
    __shared__ unsigned short kv[272 * 72];
    __shared__ float sim[16 * 273];
    __shared__ float qs[16 * 68];
    __shared__ float red[64];

    const int bt = blockIdx.x >> 4, h = blockIdx.x & 15;
    const int tid = threadIdx.x;
    const int lane = tid & 63, wave = tid >> 6;
    const int r = tid & 15, grp = tid >> 4;

    const unsigned short* kt = kbase + (size_t)bt * KV_BTSTR + (size_t)h * KV_HSTR;

    {
        const int qi = tid >> 4, d0 = (tid & 15) * 4;
        const unsigned short* src = qkvl + (size_t)(bt * 16 + qi) * 3072 + h * 64 + d0;
        qs[qi * 68 + d0 + 0] = bf2f(src[0]);
        qs[qi * 68 + d0 + 1] = bf2f(src[1]);
        qs[qi * 68 + d0 + 2] = bf2f(src[2]);
        qs[qi * 68 + d0 + 3] = bf2f(src[3]);
    }
    // stage K into LDS
#pragma unroll
    for (int i = 0; i < 9; ++i) {
        int idx = i * 256 + tid;
        if (idx < 2176) {
            int f = idx >> 3, cp = idx & 7;
            const unsigned short* src = (f < 256)
                ? kt + f * 64 + cp * 8
                : qkvl + (size_t)(bt * 16 + (f - 256)) * 3072 + 1024 + h * 64 + cp * 8;
            *(short8*)&kv[f * 72 + cp * 8] = *(const short8*)src;
        }
    }
    // T14: issue V loads now (into registers); they stay in flight across the
    // lgkm-only barriers and drain just before the V ds_write phase.
    short8 vreg[9];
#pragma unroll
    for (int i = 0; i < 9; ++i) {
        int idx = i * 256 + tid;
        if (idx < 2176) {
            int f = idx >> 3, cp = idx & 7;
            const unsigned short* src = (f < 256)
                ? kt + KV_PSLOT + f * 64 + cp * 8
                : qkvl + (size_t)(bt * 16 + (f - 256)) * 3072 + 2048 + h * 64 + cp * 8;
            vreg[i] = *(const short8*)src;
        }
    }
    BARL();                                        // S0: q/K LDS writes drained

    float p[17];
#pragma unroll
    for (int i = 0; i < 17; ++i) p[i] = 0.f;
#pragma unroll
    for (int d = 0; d < 64; d += 8) {
        float q8[8];
#pragma unroll
        for (int j = 0; j < 8; ++j) q8[j] = qs[r * 68 + d + j];
#pragma unroll
        for (int i = 0; i < 17; ++i) {
            short8 k8 = *(const short8*)&kv[(grp + i * 16) * 72 + d];
#pragma unroll
            for (int j = 0; j < 8; ++j) p[i] += q8[j] * bf2f((unsigned short)k8[j]);
        }
    }
    float mx = -3.0e38f;
#pragma unroll
    for (int i = 0; i < 17; ++i) mx = fmaxf(mx, p[i]);
    mx = fmaxf(mx, __shfl_xor(mx, 16));
    mx = fmaxf(mx, __shfl_xor(mx, 32));
    if (lane < 16) red[wave * 16 + lane] = mx;
    BARL();                                        // S1: dots done, red(max) ready
    const float rowmax = fmaxf(fmaxf(red[r], red[16 + r]), fmaxf(red[32 + r], red[48 + r]));

    float sm = 0.f;
#pragma unroll
    for (int i = 0; i < 17; ++i) { p[i] = __expf(p[i] - rowmax); sm += p[i]; }
    sm += __shfl_xor(sm, 16);
    sm += __shfl_xor(sm, 32);
#pragma unroll
    for (int i = 0; i < 17; ++i) sim[r * 273 + grp + i * 16] = p[i];
    BARL();                                        // S2: red(max) reads done
    if (lane < 16) red[wave * 16 + lane] = sm;
    // V: pure ds_writes from registers (vmcnt waits auto-inserted on vreg)
#pragma unroll
    for (int i = 0; i < 9; ++i) {
        int idx = i * 256 + tid;
        if (idx < 2176) {
            int f = idx >> 3, cp = idx & 7;
            *(short8*)&kv[f * 72 + cp * 8] = vreg[i];
        }
    }
    BARL();                                        // S3: sim + red(sum) + V ready
    const float inv = 1.0f / (red[r] + red[16 + r] + red[32 + r] + red[48 + r]);

    float o0 = 0.f, o1 = 0.f, o2 = 0.f, o3 = 0.f;
    for (int f = 0; f < 272; ++f) {
        float pv = sim[r * 273 + f];
        short4v v4 = *(const short4v*)&kv[f * 72 + grp * 4];
        o0 += pv * bf2f((unsigned short)v4[0]);
        o1 += pv * bf2f((unsigned short)v4[1]);
        o2 += pv * bf2f((unsigned short)v4[2]);
        o3 += pv * bf2f((unsigned short)v4[3]);
    }
    unsigned short* dst = o + (size_t)(bt * 16 + r) * 1024 + h * 64 + grp * 4;
    dst[0] = f2bf(o0 * inv);
    dst[1] = f2bf(o1 * inv);
    dst[2] = f2bf(o2 * inv);
    dst[3] = f2bf(o3 * inv);
}

// ---------------------------------------------------------------------------
extern "C" void kernel_launch(void* const* d_in, const int* in_sizes, int n_in,
                              void* d_out, int out_size, void* d_ws, size_t ws_size,
                              hipStream_t stream)
{
    const float* x_f      = (const float*)d_in[0];
    const float* goal_w1  = (const float*)d_in[1];
    const float* goal_b1  = (const float*)d_in[2];
    const float* goal_w2  = (const float*)d_in[3];
    const float* goal_b2  = (const float*)d_in[4];
    const float* latents  = (const float*)d_in[5];
    const float* tpos     = (const float*)d_in[6];
    const float* lnm_g    = (const float*)d_in[7];
    const float* lnm_b    = (const float*)d_in[8];
    const float* lnl_g    = (const float*)d_in[9];
    const float* lnl_b    = (const float*)d_in[10];
    const float* wq       = (const float*)d_in[11];
    const float* wk       = (const float*)d_in[12];
    const float* wv       = (const float*)d_in[13];
    const float* wo       = (const float*)d_in[14];
    const float* ffn_g    = (const float*)d_in[15];
    const float* ffn_b    = (const float*)d_in[16];
    const float* ffw1     = (const float*)d_in[17];
    const float* ffb1     = (const float*)d_in[18];
    const float* ffw2     = (const float*)d_in[19];
    const float* ffb2     = (const float*)d_in[20];
    const float* fin_g    = (const float*)d_in[21];
    const float* fin_b    = (const float*)d_in[22];

    char* ws = (char*)d_ws;
    size_t off = 0;
    auto alloc = [&](size_t bytes) -> char* {
        char* p = ws + off;
        off += (bytes + 255) & ~(size_t)255;
        return p;
    };
    typedef unsigned short u16;
    u16*   wg1t   = (u16*)  alloc(2048ull * 1280 * 2);
    u16*   wg2t   = (u16*)  alloc(1024ull * 2048 * 2);
    u16*   wqkvl  = (u16*)  alloc(6ull * 3072 * 1024 * 2);
    u16*   wkvm   = (u16*)  alloc(6ull * 2048 * 1024 * 2);
    u16*   wot    = (u16*)  alloc(6ull * 1024 * 1024 * 2);
    u16*   wf1t   = (u16*)  alloc(6ull * 4096 * 1024 * 2);
    u16*   wf2t   = (u16*)  alloc(6ull * 1024 * 4096 * 2);
    float* biaskv = (float*)alloc(6ull * 2048 * 4);
    float* bpart  = (float*)alloc(384ull * 256 * 4);
    float* xres   = (float*)alloc(2048ull * 1024 * 4);
    u16*   latn   = (u16*)  alloc(2048ull * 1024 * 2);
    u16*   qkvl   = (u16*)  alloc(2048ull * 3072 * 2);
    u16*   obuf   = (u16*)  alloc(2048ull * 1024 * 2);
    u16*   ffny   = (u16*)  alloc(2048ull * 1024 * 2);
    u16*   ffnmid = (u16*)  alloc(2048ull * 4096 * 2);
    u16*   bufB   = (u16*)  alloc(32768ull * 1024 * 2);   // goal output, bf16
    u16*   bufC   = (u16*)  alloc(41943040ull * 2);       // x_f bf16, then nf
    if (off > ws_size) return;
    // bufA last: grouped-KV buffer. Pick largest G in {6,3,2,1} that fits.
    const size_t singleBytes = 32768ull * 2048 * 2;       // per-layer KV = 134 MB
    int G = 1;
    if (off + 6 * singleBytes <= ws_size)      G = 6;
    else if (off + 3 * singleBytes <= ws_size) G = 3;
    else if (off + 2 * singleBytes <= ws_size) G = 2;
    u16* bufA = (u16*)alloc((size_t)G * singleBytes);
    if (off > ws_size) return;
    const int kvN = G * 2048;

    // ---- phase 0: conversions / folds ----
    convert_bf16<<<40960, 256, 0, stream>>>(x_f, bufC, 41943040ull / 4);
    transpose_w<<<dim3(32, 20, 1), 256, 0, stream>>>(goal_w1, wg1t, nullptr, 1.f, 1280, 2048, 0, 0, 0);
    transpose_w<<<dim3(16, 32, 1), 256, 0, stream>>>(goal_w2, wg2t, nullptr, 1.f, 2048, 1024, 0, 0, 0);
    transpose_w<<<dim3(16, 16, 6), 256, 0, stream>>>(wq, wqkvl,                nullptr, 0.125f, 1024, 1024, 1024ull*1024, 3072ull*1024, 0);
    transpose_w<<<dim3(16, 16, 6), 256, 0, stream>>>(wk, wqkvl + 1024ull*1024, nullptr, 1.f,    1024, 1024, 1024ull*1024, 3072ull*1024, 0);
    transpose_w<<<dim3(16, 16, 6), 256, 0, stream>>>(wv, wqkvl + 2048ull*1024, nullptr, 1.f,    1024, 1024, 1024ull*1024, 3072ull*1024, 0);
    transpose_w<<<dim3(16, 16, 6), 256, 0, stream>>>(wk, wkvm,                 lnm_g,   1.f,    1024, 1024, 1024ull*1024, 2048ull*1024, 1024);
    transpose_w<<<dim3(16, 16, 6), 256, 0, stream>>>(wv, wkvm + 1024ull*1024,  lnm_g,   1.f,    1024, 1024, 1024ull*1024, 2048ull*1024, 1024);
    transpose_w<<<dim3(16, 16, 6), 256, 0, stream>>>(wo, wot,                  nullptr, 1.f,    1024, 1024, 1024ull*1024, 1024ull*1024, 0);
    transpose_w<<<dim3(64, 16, 6), 256, 0, stream>>>(ffw1, wf1t,               nullptr, 1.f,    1024, 4096, 4096ull*1024, 4096ull*1024, 0);
    transpose_w<<<dim3(16, 64, 6), 256, 0, stream>>>(ffw2, wf2t,               nullptr, 1.f,    4096, 1024, 4096ull*1024, 4096ull*1024, 0);
    fold_bias_part<<<dim3(48, 8), 256, 0, stream>>>(wk, wv, lnm_b, bpart);
    fold_bias_red<<<48, 256, 0, stream>>>(bpart, biaskv);
    init_x<<<2048, 256, 0, stream>>>(latents, xres);

    // ---- goal MLP ----
    gemm_bt<E_BIAS_GELU_BF16, 0><<<256 * 16, 256, 0, stream>>>(bufC, wg1t, bufA, goal_b1, nullptr, nullptr, 32768, 2048, 1280);
    gemm_bt<E_BIAS_TPOS_BF16, 0><<<256 * 8, 256, 0, stream>>>(bufA, wg2t, bufB, goal_b2, nullptr, tpos, 32768, 1024, 2048);
    ln_k<false, true, true><<<32768, 256, 0, stream>>>(bufB, nullptr, nullptr, bufC);   // nf

    // ---- depth loop (grouped KV: one merged GEMM per G layers, blocked layout) ----
    for (int i = 0; i < 6; ++i) {
        const u16* wqkvl_i = wqkvl + (size_t)i * 3072 * 1024;
        const u16* wot_i   = wot   + (size_t)i * 1024 * 1024;
        const u16* wf1_i   = wf1t  + (size_t)i * 4096 * 1024;
        const u16* wf2_i   = wf2t  + (size_t)i * 1024 * 4096;

        if ((i % G) == 0) {
            gemm_bt<E_BIAS_BF16, 1><<<G * 4096, 256, 0, stream>>>(
                bufC, wkvm + (size_t)i * 2048 * 1024, bufA,
                biaskv + i * 2048, nullptr, nullptr, 32768, kvN, 1024);
        }

        ln_k<true, true, false><<<2048, 256, 0, stream>>>(xres, lnl_g + i * 1024, lnl_b + i * 1024, latn);
        gemm64<E_BF16><<<32 * 24, 256, 0, stream>>>(latn, wqkvl_i, qkvl, nullptr, nullptr, 2048, 3072, 1024);
        attn_k<<<2048, 256, 0, stream>>>(qkvl, bufA + (size_t)(2 * (i % G)) * KV_PSLOT, obuf);
        gemm3232<E_ADD_F32><<<32 * 16, 256, 0, stream>>>(obuf, wot_i, xres, nullptr, xres, 2048, 1024, 1024);
        ln_k<true, true, false><<<2048, 256, 0, stream>>>(xres, ffn_g + i * 1024, ffn_b + i * 1024, ffny);
        gemm64<E_BIAS_GELU_BF16><<<32 * 32, 256, 0, stream>>>(ffny, wf1_i, ffnmid, ffb1 + i * 4096, nullptr, 2048, 4096, 1024);
        gemm3232<E_BIAS_ADD_F32><<<32 * 16, 256, 0, stream>>>(ffnmid, wf2_i, xres, ffb2 + i * 1024, xres, 2048, 1024, 4096);
    }

    // ---- final LN -> d_out (f32) ----
    ln_k<true, false, false><<<2048, 256, 0, stream>>>(xres, fin_g, fin_b, d_out);
}

// Round 19
// 2625.165 us; speedup vs baseline: 1.0344x; 1.0055x over previous
//
#include <hip/hip_runtime.h>
#include <math.h>

#define DEV __device__ __forceinline__

typedef __attribute__((ext_vector_type(8))) short short8;
typedef __attribute__((ext_vector_type(4))) short short4v;
typedef __attribute__((ext_vector_type(4))) float f32x4;
typedef __attribute__((ext_vector_type(8))) __bf16 bf16x8;

DEV float bf2f(unsigned short u) {
    union { unsigned int i; float f; } c; c.i = ((unsigned int)u) << 16; return c.f;
}
DEV unsigned short f2bf(float f) {
    union { float f; unsigned int i; } c; c.f = f;
    unsigned int u = c.i;
    u += 0x7fffu + ((u >> 16) & 1u);   // RNE
    return (unsigned short)(u >> 16);
}
DEV float gelu_exact(float x) { return 0.5f * x * (1.0f + erff(x * 0.70710678118654752f)); }

DEV f32x4 MF(bf16x8 a, bf16x8 b, f32x4 c) {
    return __builtin_amdgcn_mfma_f32_16x16x32_bf16(a, b, c, 0, 0, 0);
}

#define GLL16(g, l)                                                                   \
    __builtin_amdgcn_global_load_lds(                                                \
        (const __attribute__((address_space(1))) unsigned int*)(g),                  \
        (__attribute__((address_space(3))) unsigned int*)(l), 16, 0, 0)

// lgkm-only barrier (m201 pattern): drains DS ops but leaves global loads
// in flight across the barrier (T14 async-stage prerequisite).
#define BARL() do { asm volatile("s_waitcnt lgkmcnt(0)" ::: "memory");                \
                    __builtin_amdgcn_s_barrier(); } while (0)

// blocked-KV geometry: per (layer,part) slot = 128 bt x 16 h x 256 f x 64 d u16
#define KV_HSTR   16384ull                 // h stride (256*64)
#define KV_BTSTR  262144ull                // bt stride (16*16384)
#define KV_PSLOT  33554432ull              // (s*2+p) slot stride (128*262144)

// ---------------------------------------------------------------------------
// Weight transpose + f32->bf16 convert: in (K,N) f32 row-major -> out (N,K) bf16.
// ---------------------------------------------------------------------------
__global__ __launch_bounds__(256)
void transpose_w(const float* __restrict__ in, unsigned short* __restrict__ out,
                 const float* __restrict__ rowscale, float uscale,
                 int K, int N, size_t inStride, size_t outStride, int scaleStride)
{
    __shared__ float tile[64][65];
    in  += (size_t)blockIdx.z * inStride;
    out += (size_t)blockIdx.z * outStride;
    const int k0 = blockIdx.y * 64, n0 = blockIdx.x * 64;
    const int tid = threadIdx.x;
    const int c = tid & 63;
#pragma unroll
    for (int i = 0; i < 16; ++i) {
        int rr = (i << 2) + (tid >> 6);
        float v = in[(size_t)(k0 + rr) * N + n0 + c];
        if (rowscale) v *= rowscale[(size_t)blockIdx.z * scaleStride + k0 + rr];
        tile[rr][c] = v * uscale;
    }
    __syncthreads();
#pragma unroll
    for (int i = 0; i < 16; ++i) {
        int rr = (i << 2) + (tid >> 6);
        out[(size_t)(n0 + rr) * K + k0 + c] = f2bf(tile[c][rr]);
    }
}

// K-split partial: bpart[(blk48*8 + ks)*256 + tid] = sum over 128 rows
__global__ __launch_bounds__(256)
void fold_bias_part(const float* __restrict__ wk, const float* __restrict__ wv,
                    const float* __restrict__ bmed, float* __restrict__ bpart)
{
    const int d = blockIdx.x >> 3;
    const int rem = blockIdx.x & 7;
    const int part = rem >> 2;
    const int chunk = rem & 3;
    const int r0 = blockIdx.y * 128;
    const float* w = (part ? wv : wk) + (size_t)d * 1024 * 1024 + chunk * 256 + threadIdx.x;
    const float* b = bmed + d * 1024;
    float acc = 0.f;
    for (int r = r0; r < r0 + 128; ++r) acc += b[r] * w[(size_t)r * 1024];
    bpart[(size_t)(blockIdx.x * 8 + blockIdx.y) * 256 + threadIdx.x] = acc;
}

// deterministic reduce of the 8 k-slices
__global__ __launch_bounds__(256)
void fold_bias_red(const float* __restrict__ bpart, float* __restrict__ biaskv)
{
    const int d = blockIdx.x >> 3;
    const int rem = blockIdx.x & 7;
    const int part = rem >> 2;
    const int chunk = rem & 3;
    float acc = 0.f;
#pragma unroll
    for (int k = 0; k < 8; ++k)
        acc += bpart[(size_t)(blockIdx.x * 8 + k) * 256 + threadIdx.x];
    biaskv[d * 2048 + part * 1024 + chunk * 256 + threadIdx.x] = acc;
}

__global__ __launch_bounds__(256)
void convert_bf16(const float* __restrict__ in, unsigned short* __restrict__ out, size_t n4)
{
    size_t i = (size_t)blockIdx.x * 256 + threadIdx.x;
    if (i >= n4) return;
    float4 v = ((const float4*)in)[i];
    ushort4 u;
    u.x = f2bf(v.x); u.y = f2bf(v.y); u.z = f2bf(v.z); u.w = f2bf(v.w);
    ((ushort4*)out)[i] = u;
}

__global__ __launch_bounds__(256)
void init_x(const float* __restrict__ lat, float* __restrict__ x)
{
    const int row = blockIdx.x;
    ((float4*)x)[(size_t)row * 256 + threadIdx.x] =
        ((const float4*)lat)[(size_t)(row & 255) * 256 + threadIdx.x];
}

// ---------------------------------------------------------------------------
// LayerNorm over D=1024, one row per block. INBF: input is bf16 (u16).
// ---------------------------------------------------------------------------
template<bool AFFINE, bool OUTBF, bool INBF>
__global__ __launch_bounds__(256)
void ln_k(const void* __restrict__ in_, const float* __restrict__ g,
          const float* __restrict__ b, void* __restrict__ out)
{
    const int row = blockIdx.x;
    const int tid = threadIdx.x;
    float4 v;
    if (INBF) {
        ushort4 u = ((const ushort4*)((const unsigned short*)in_ + (size_t)row * 1024))[tid];
        v.x = bf2f(u.x); v.y = bf2f(u.y); v.z = bf2f(u.z); v.w = bf2f(u.w);
    } else {
        v = ((const float4*)((const float*)in_ + (size_t)row * 1024))[tid];
    }
    float s  = v.x + v.y + v.z + v.w;
    float ss = v.x * v.x + v.y * v.y + v.z * v.z + v.w * v.w;
#pragma unroll
    for (int o = 32; o > 0; o >>= 1) { s += __shfl_down(s, o); ss += __shfl_down(ss, o); }
    __shared__ float red[8];
    if ((tid & 63) == 0) { red[tid >> 6] = s; red[4 + (tid >> 6)] = ss; }
    __syncthreads();
    const float sum  = red[0] + red[1] + red[2] + red[3];
    const float ssum = red[4] + red[5] + red[6] + red[7];
    const float mean = sum * (1.0f / 1024.0f);
    const float var  = ssum * (1.0f / 1024.0f) - mean * mean;
    const float rs   = rsqrtf(var + 1e-5f);
    float o0 = (v.x - mean) * rs, o1 = (v.y - mean) * rs;
    float o2 = (v.z - mean) * rs, o3 = (v.w - mean) * rs;
    if (AFFINE) {
        float4 gv = ((const float4*)g)[tid];
        float4 bv = ((const float4*)b)[tid];
        o0 = o0 * gv.x + bv.x; o1 = o1 * gv.y + bv.y;
        o2 = o2 * gv.z + bv.z; o3 = o3 * gv.w + bv.w;
    }
    if (OUTBF) {
        ushort4 u; u.x = f2bf(o0); u.y = f2bf(o1); u.z = f2bf(o2); u.w = f2bf(o3);
        ((ushort4*)out)[(size_t)row * 256 + tid] = u;
    } else {
        float4 ov; ov.x = o0; ov.y = o1; ov.z = o2; ov.w = o3;
        ((float4*)out)[(size_t)row * 256 + tid] = ov;
    }
}

enum { E_BF16 = 0, E_BIAS_BF16, E_BIAS_GELU_BF16, E_BIAS_TPOS_BF16, E_ADD_F32, E_BIAS_ADD_F32 };

// ---------------------------------------------------------------------------
// Big-shape GEMM: 128x128 tile, BK=64, 4 waves, 32 KB LDS (~3 blocks/CU),
// global_load_lds with pre-swizzled source, conflict-free swizzled
// ds_read_b128 (cp = c ^ (row&7)), bijective XCD swizzle.
// MODE 0: flat output. MODE 1 ("grouped KV", measured 1.63x faster/layer):
// N = G*2048, grid = G*4096; per-XCD iteration s-group -> by -> bx keeps each
// group's B panel L2-resident. MODE-1 epilogue writes HEAD-BLOCKED layout
// [(s*2+p)*128+bt][h][f][d] so attention reads contiguous 32 KB tiles.
// C(M,N) = A(M,K) @ Bt(N,K)^T.
// ---------------------------------------------------------------------------
template<int EPI, int MODE>
__global__ __launch_bounds__(256, 2)
void gemm_bt(const unsigned short* __restrict__ A, const unsigned short* __restrict__ Bt,
             void* __restrict__ Out,
             const float* __restrict__ bias, const float* __restrict__ addsrc,
             const float* __restrict__ tpos,
             int M, int N, int K)
{
    __shared__ unsigned short lds[2 * 128 * 64];
    const int tid  = threadIdx.x;
    const int wave = tid >> 6, lane = tid & 63;
    const int nbx  = N >> 7;

    int by, bx;
    if (MODE == 1) {
        const int u = blockIdx.x >> 3;
        const int s = u >> 9;                  // depth group
        const int v = u & 511;
        by = (blockIdx.x & 7) * 32 + (v >> 4); // 0..255
        bx = s * 16 + (v & 15);
    } else {
        const int nwg = gridDim.x;
        int bid = blockIdx.x;
        int wg = ((nwg & 7) == 0) ? ((bid & 7) * (nwg >> 3) + (bid >> 3)) : bid;
        by = wg / nbx; bx = wg % nbx;
    }

    const int swz = ((lane & 7) ^ (lane >> 3)) * 8;
    const unsigned short* gA = A  + (size_t)(by * 128 + (lane >> 3)) * K + swz;
    const unsigned short* gB = Bt + (size_t)(bx * 128 + (lane >> 3)) * K + swz;

    const int wr = wave >> 1, wc = wave & 1;
    f32x4 acc[4][4] = {};

    unsigned short* ldsA = lds;
    unsigned short* ldsB = lds + 128 * 64;

    const int off0 = (((lane >> 4)    ) ^ (lane & 7)) * 8;
    const int off1 = (((lane >> 4) | 4) ^ (lane & 7)) * 8;
    const unsigned short* la = ldsA + (wr * 64 + (lane & 15)) * 64;
    const unsigned short* lb = ldsB + (wc * 64 + (lane & 15)) * 64;

    for (int kt = 0; kt < K; kt += 64) {
#pragma unroll
        for (int j = 0; j < 4; ++j) {
            const int chunk = (j << 2) + wave;   // wave-uniform
            GLL16(gA + (size_t)chunk * 8 * K + kt, ldsA + chunk * 512);
            GLL16(gB + (size_t)chunk * 8 * K + kt, ldsB + chunk * 512);
        }
        __syncthreads();
#pragma unroll
        for (int kk = 0; kk < 2; ++kk) {
            const int offk = kk ? off1 : off0;
            bf16x8 a[4], b[4];
#pragma unroll
            for (int m = 0; m < 4; ++m) a[m] = *(const bf16x8*)(la + m * 1024 + offk);
#pragma unroll
            for (int n = 0; n < 4; ++n) b[n] = *(const bf16x8*)(lb + n * 1024 + offk);
#pragma unroll
            for (int m = 0; m < 4; ++m)
#pragma unroll
                for (int n = 0; n < 4; ++n)
                    acc[m][n] = MF(a[m], b[n], acc[m][n]);
        }
        __syncthreads();
    }

    // epilogue: C/D layout col = lane&15, row = (lane>>4)*4 + reg  [m89-verified]
    const int r0 = by * 128 + wr * 64 + (lane >> 4) * 4;
    const int c0 = bx * 128 + wc * 64 + (lane & 15);
#pragma unroll
    for (int m = 0; m < 4; ++m) {
#pragma unroll
        for (int n = 0; n < 4; ++n) {
            const int c = c0 + n * 16;
            float bv = 0.f;
            if (EPI == E_BIAS_BF16 || EPI == E_BIAS_GELU_BF16 ||
                EPI == E_BIAS_TPOS_BF16 || EPI == E_BIAS_ADD_F32)
                bv = bias[c];
            // blocked-KV decomposition (MODE 1)
            const int s  = c >> 11;
            const int cx = c & 2047;
            const int p  = cx >> 10, hx = (cx >> 6) & 15, d = cx & 63;
#pragma unroll
            for (int j = 0; j < 4; ++j) {
                const int r = r0 + m * 16 + j;
                float v = acc[m][n][j] + bv;
                if (EPI == E_BIAS_GELU_BF16) v = gelu_exact(v);
                if (EPI == E_BIAS_TPOS_BF16) v += tpos[(((unsigned)r >> 8) & 15) * 1024 + c];
                if (EPI == E_ADD_F32 || EPI == E_BIAS_ADD_F32) v += addsrc[(size_t)r * N + c];
                if (MODE == 1) {
                    const int bt = r >> 8, f = r & 255;
                    ((unsigned short*)Out)[(size_t)((s * 2 + p) * 128 + bt) * KV_BTSTR +
                                           (size_t)hx * KV_HSTR + f * 64 + d] = f2bf(v);
                } else if (EPI == E_ADD_F32 || EPI == E_BIAS_ADD_F32) {
                    ((float*)Out)[(size_t)r * N + c] = v;
                } else {
                    ((unsigned short*)Out)[(size_t)r * N + c] = f2bf(v);
                }
            }
        }
    }
}

// ---------------------------------------------------------------------------
// Latent-stack GEMM: 64x128 tile, BK=64, 4 waves, 24 KB LDS, m97 skeleton +
// zero-conflict swizzle (r4-verified). Used for qkv (grid 768), ffn1 (1024).
// ---------------------------------------------------------------------------
template<int EPI>
__global__ __launch_bounds__(256, 4)
void gemm64(const unsigned short* __restrict__ A, const unsigned short* __restrict__ Bt,
            void* __restrict__ Out,
            const float* __restrict__ bias, const float* __restrict__ addsrc,
            int M, int N, int K)
{
    __shared__ unsigned short lds[64 * 64 + 128 * 64];
    const int tid  = threadIdx.x;
    const int wave = tid >> 6, lane = tid & 63;
    const int nbx  = N >> 7;

    const int nwg = gridDim.x;
    int bid = blockIdx.x;
    int wg = ((nwg & 7) == 0) ? ((bid & 7) * (nwg >> 3) + (bid >> 3)) : bid;
    const int by = wg / nbx, bx = wg % nbx;

    const int swz = ((lane & 7) ^ (lane >> 3)) * 8;
    const unsigned short* gA = A  + (size_t)(by * 64  + (lane >> 3)) * K + swz;
    const unsigned short* gB = Bt + (size_t)(bx * 128 + (lane >> 3)) * K + swz;

    const int wr = wave >> 1, wc = wave & 1;
    f32x4 acc[2][4] = {};

    unsigned short* ldsA = lds;
    unsigned short* ldsB = lds + 64 * 64;

    const int off0 = (((lane >> 4)    ) ^ (lane & 7)) * 8;
    const int off1 = (((lane >> 4) | 4) ^ (lane & 7)) * 8;
    const unsigned short* la = ldsA + (wr * 32 + (lane & 15)) * 64;
    const unsigned short* lb = ldsB + (wc * 64 + (lane & 15)) * 64;

    for (int kt = 0; kt < K; kt += 64) {
        GLL16(gA + (size_t)(wave)     * 8 * K + kt, ldsA + (wave)      * 512);
        GLL16(gA + (size_t)(4 + wave) * 8 * K + kt, ldsA + (4 + wave)  * 512);
#pragma unroll
        for (int j = 0; j < 4; ++j) {
            const int chunk = (j << 2) + wave;
            GLL16(gB + (size_t)chunk * 8 * K + kt, ldsB + chunk * 512);
        }
        __syncthreads();
#pragma unroll
        for (int kk = 0; kk < 2; ++kk) {
            const int offk = kk ? off1 : off0;
            bf16x8 a[2], b[4];
#pragma unroll
            for (int m = 0; m < 2; ++m) a[m] = *(const bf16x8*)(la + m * 1024 + offk);
#pragma unroll
            for (int n = 0; n < 4; ++n) b[n] = *(const bf16x8*)(lb + n * 1024 + offk);
#pragma unroll
            for (int m = 0; m < 2; ++m)
#pragma unroll
                for (int n = 0; n < 4; ++n)
                    acc[m][n] = MF(a[m], b[n], acc[m][n]);
        }
        __syncthreads();
    }

    const int r0 = by * 64 + wr * 32 + (lane >> 4) * 4;
    const int c0 = bx * 128 + wc * 64 + (lane & 15);
#pragma unroll
    for (int m = 0; m < 2; ++m) {
#pragma unroll
        for (int n = 0; n < 4; ++n) {
            const int c = c0 + n * 16;
#pragma unroll
            for (int j = 0; j < 4; ++j) {
                const int r = r0 + m * 16 + j;
                float v = acc[m][n][j];
                if (EPI == E_BIAS_BF16 || EPI == E_BIAS_GELU_BF16 || EPI == E_BIAS_ADD_F32)
                    v += bias[c];
                if (EPI == E_BIAS_GELU_BF16) v = gelu_exact(v);
                if (EPI == E_ADD_F32 || EPI == E_BIAS_ADD_F32) v += addsrc[(size_t)r * N + c];
                if (EPI == E_ADD_F32 || EPI == E_BIAS_ADD_F32)
                    ((float*)Out)[(size_t)r * N + c] = v;
                else
                    ((unsigned short*)Out)[(size_t)r * N + c] = f2bf(v);
            }
        }
    }
}

// ---------------------------------------------------------------------------
// Small-N GEMM: 64x64 tile, BK=64, 4 waves (wave-tile 32x32), 16 KB LDS ->
// 4 blocks/CU. For wo and ffn2 (N=1024): grid 512 (r9/r11 A/B-measured best).
// ---------------------------------------------------------------------------
template<int EPI>
__global__ __launch_bounds__(256, 4)
void gemm3232(const unsigned short* __restrict__ A, const unsigned short* __restrict__ Bt,
              void* __restrict__ Out,
              const float* __restrict__ bias, const float* __restrict__ addsrc,
              int M, int N, int K)
{
    __shared__ unsigned short lds[2 * 64 * 64];    // A then B, 16 KiB
    const int tid  = threadIdx.x;
    const int wave = tid >> 6, lane = tid & 63;
    const int nbx  = N >> 6;

    const int nwg = gridDim.x;
    int bid = blockIdx.x;
    int wg = ((nwg & 7) == 0) ? ((bid & 7) * (nwg >> 3) + (bid >> 3)) : bid;
    const int by = wg / nbx, bx = wg % nbx;

    const int swz = ((lane & 7) ^ (lane >> 3)) * 8;
    const unsigned short* gA = A  + (size_t)(by * 64 + (lane >> 3)) * K + swz;
    const unsigned short* gB = Bt + (size_t)(bx * 64 + (lane >> 3)) * K + swz;

    const int wr = wave >> 1, wc = wave & 1;
    f32x4 acc[2][2] = {};

    unsigned short* ldsA = lds;
    unsigned short* ldsB = lds + 64 * 64;

    const int off0 = (((lane >> 4)    ) ^ (lane & 7)) * 8;
    const int off1 = (((lane >> 4) | 4) ^ (lane & 7)) * 8;
    const unsigned short* la = ldsA + (wr * 32 + (lane & 15)) * 64;
    const unsigned short* lb = ldsB + (wc * 32 + (lane & 15)) * 64;

    for (int kt = 0; kt < K; kt += 64) {
        GLL16(gA + (size_t)(wave)     * 8 * K + kt, ldsA + (wave)      * 512);
        GLL16(gA + (size_t)(4 + wave) * 8 * K + kt, ldsA + (4 + wave)  * 512);
        GLL16(gB + (size_t)(wave)     * 8 * K + kt, ldsB + (wave)      * 512);
        GLL16(gB + (size_t)(4 + wave) * 8 * K + kt, ldsB + (4 + wave)  * 512);
        __syncthreads();
#pragma unroll
        for (int kk = 0; kk < 2; ++kk) {
            const int offk = kk ? off1 : off0;
            bf16x8 a[2], b[2];
#pragma unroll
            for (int m = 0; m < 2; ++m) a[m] = *(const bf16x8*)(la + m * 1024 + offk);
#pragma unroll
            for (int n = 0; n < 2; ++n) b[n] = *(const bf16x8*)(lb + n * 1024 + offk);
#pragma unroll
            for (int m = 0; m < 2; ++m)
#pragma unroll
                for (int n = 0; n < 2; ++n)
                    acc[m][n] = MF(a[m], b[n], acc[m][n]);
        }
        __syncthreads();
    }

    const int r0 = by * 64 + wr * 32 + (lane >> 4) * 4;
    const int c0 = bx * 64 + wc * 32 + (lane & 15);
#pragma unroll
    for (int m = 0; m < 2; ++m) {
#pragma unroll
        for (int n = 0; n < 2; ++n) {
            const int c = c0 + n * 16;
#pragma unroll
            for (int j = 0; j < 4; ++j) {
                const int r = r0 + m * 16 + j;
                float v = acc[m][n][j];
                if (EPI == E_BIAS_BF16 || EPI == E_BIAS_GELU_BF16 || EPI == E_BIAS_ADD_F32)
                    v += bias[c];
                if (EPI == E_BIAS_GELU_BF16) v = gelu_exact(v);
                if (EPI == E_ADD_F32 || EPI == E_BIAS_ADD_F32) v += addsrc[(size_t)r * N + c];
                if (EPI == E_ADD_F32 || EPI == E_BIAS_ADD_F32)
                    ((float*)Out)[(size_t)r * N + c] = v;
                else
                    ((unsigned short*)Out)[(size_t)r * N + c] = f2bf(v);
            }
        }
    }
}

// ---------------------------------------------------------------------------
// Attention v4 (T14 async-V + vectorized LDS reads): one block per (bt, head).
// Q=16, F=272, DH=64. sim stride 276 (f32x4-aligned); PV unrolled x4 with one
// float4 sim read per 4 V-rows; qs read as 2x float4 per d-step. Bank audit:
// both patterns 2-way aliased = free (m136). LDS = 60 KB -> 2 blocks/CU
// (unchanged). Arithmetic identical to r18.
// ---------------------------------------------------------------------------
__global__ __launch_bounds__(256)
void attn_k(const unsigned short* __restrict__ qkvl, const unsigned short* __restrict__ kbase,
            unsigned short* __restrict__ o)
{
    __shared__ unsigned short kv[272 * 72];
    __shared__ float sim[16 * 276];
    __shared__ float qs[16 * 68];
    __shared__ float red[64];

    const int bt = blockIdx.x >> 4, h = blockIdx.x & 15;
    const int tid = threadIdx.x;
    const int lane = tid & 63, wave = tid >> 6;
    const int r = tid & 15, grp = tid >> 4;

    const unsigned short* kt = kbase + (size_t)bt * KV_BTSTR + (size_t)h * KV_HSTR;

    {
        const int qi = tid >> 4, d0 = (tid & 15) * 4;
        const unsigned short* src = qkvl + (size_t)(bt * 16 + qi) * 3072 + h * 64 + d0;
        qs[qi * 68 + d0 + 0] = bf2f(src[0]);
        qs[qi * 68 + d0 + 1] = bf2f(src[1]);
        qs[qi * 68 + d0 + 2] = bf2f(src[2]);
        qs[qi * 68 + d0 + 3] = bf2f(src[3]);
    }
    // stage K into LDS
#pragma unroll
    for (int i = 0; i < 9; ++i) {
        int idx = i * 256 + tid;
        if (idx < 2176) {
            int f = idx >> 3, cp = idx & 7;
            const unsigned short* src = (f < 256)
                ? kt + f * 64 + cp * 8
                : qkvl + (size_t)(bt * 16 + (f - 256)) * 3072 + 1024 + h * 64 + cp * 8;
            *(short8*)&kv[f * 72 + cp * 8] = *(const short8*)src;
        }
    }
    // T14: issue V loads now (into registers); they stay in flight across the
    // lgkm-only barriers and drain just before the V ds_write phase.
    short8 vreg[9];
#pragma unroll
    for (int i = 0; i < 9; ++i) {
        int idx = i * 256 + tid;
        if (idx < 2176) {
            int f = idx >> 3, cp = idx & 7;
            const unsigned short* src = (f < 256)
                ? kt + KV_PSLOT + f * 64 + cp * 8
                : qkvl + (size_t)(bt * 16 + (f - 256)) * 3072 + 2048 + h * 64 + cp * 8;
            vreg[i] = *(const short8*)src;
        }
    }
    BARL();                                        // S0: q/K LDS writes drained

    float p[17];
#pragma unroll
    for (int i = 0; i < 17; ++i) p[i] = 0.f;
#pragma unroll
    for (int d = 0; d < 64; d += 8) {
        float4 qa = *(const float4*)&qs[r * 68 + d];
        float4 qb = *(const float4*)&qs[r * 68 + d + 4];
        float q8[8] = { qa.x, qa.y, qa.z, qa.w, qb.x, qb.y, qb.z, qb.w };
#pragma unroll
        for (int i = 0; i < 17; ++i) {
            short8 k8 = *(const short8*)&kv[(grp + i * 16) * 72 + d];
#pragma unroll
            for (int j = 0; j < 8; ++j) p[i] += q8[j] * bf2f((unsigned short)k8[j]);
        }
    }
    float mx = -3.0e38f;
#pragma unroll
    for (int i = 0; i < 17; ++i) mx = fmaxf(mx, p[i]);
    mx = fmaxf(mx, __shfl_xor(mx, 16));
    mx = fmaxf(mx, __shfl_xor(mx, 32));
    if (lane < 16) red[wave * 16 + lane] = mx;
    BARL();                                        // S1: dots done, red(max) ready
    const float rowmax = fmaxf(fmaxf(red[r], red[16 + r]), fmaxf(red[32 + r], red[48 + r]));

    float sm = 0.f;
#pragma unroll
    for (int i = 0; i < 17; ++i) { p[i] = __expf(p[i] - rowmax); sm += p[i]; }
    sm += __shfl_xor(sm, 16);
    sm += __shfl_xor(sm, 32);
#pragma unroll
    for (int i = 0; i < 17; ++i) sim[r * 276 + grp + i * 16] = p[i];
    BARL();                                        // S2: red(max) reads done
    if (lane < 16) red[wave * 16 + lane] = sm;
    // V: pure ds_writes from registers (vmcnt waits auto-inserted on vreg)
#pragma unroll
    for (int i = 0; i < 9; ++i) {
        int idx = i * 256 + tid;
        if (idx < 2176) {
            int f = idx >> 3, cp = idx & 7;
            *(short8*)&kv[f * 72 + cp * 8] = vreg[i];
        }
    }
    BARL();                                        // S3: sim + red(sum) + V ready
    const float inv = 1.0f / (red[r] + red[16 + r] + red[32 + r] + red[48 + r]);

    float o0 = 0.f, o1 = 0.f, o2 = 0.f, o3 = 0.f;
    for (int f = 0; f < 272; f += 4) {
        float4 pv4 = *(const float4*)&sim[r * 276 + f];
#pragma unroll
        for (int k = 0; k < 4; ++k) {
            const float pv = (k == 0) ? pv4.x : (k == 1) ? pv4.y : (k == 2) ? pv4.z : pv4.w;
            short4v v4 = *(const short4v*)&kv[(f + k) * 72 + grp * 4];
            o0 += pv * bf2f((unsigned short)v4[0]);
            o1 += pv * bf2f((unsigned short)v4[1]);
            o2 += pv * bf2f((unsigned short)v4[2]);
            o3 += pv * bf2f((unsigned short)v4[3]);
        }
    }
    unsigned short* dst = o + (size_t)(bt * 16 + r) * 1024 + h * 64 + grp * 4;
    dst[0] = f2bf(o0 * inv);
    dst[1] = f2bf(o1 * inv);
    dst[2] = f2bf(o2 * inv);
    dst[3] = f2bf(o3 * inv);
}

// ---------------------------------------------------------------------------
extern "C" void kernel_launch(void* const* d_in, const int* in_sizes, int n_in,
                              void* d_out, int out_size, void* d_ws, size_t ws_size,
                              hipStream_t stream)
{
    const float* x_f      = (const float*)d_in[0];
    const float* goal_w1  = (const float*)d_in[1];
    const float* goal_b1  = (const float*)d_in[2];
    const float* goal_w2  = (const float*)d_in[3];
    const float* goal_b2  = (const float*)d_in[4];
    const float* latents  = (const float*)d_in[5];
    const float* tpos     = (const float*)d_in[6];
    const float* lnm_g    = (const float*)d_in[7];
    const float* lnm_b    = (const float*)d_in[8];
    const float* lnl_g    = (const float*)d_in[9];
    const float* lnl_b    = (const float*)d_in[10];
    const float* wq       = (const float*)d_in[11];
    const float* wk       = (const float*)d_in[12];
    const float* wv       = (const float*)d_in[13];
    const float* wo       = (const float*)d_in[14];
    const float* ffn_g    = (const float*)d_in[15];
    const float* ffn_b    = (const float*)d_in[16];
    const float* ffw1     = (const float*)d_in[17];
    const float* ffb1     = (const float*)d_in[18];
    const float* ffw2     = (const float*)d_in[19];
    const float* ffb2     = (const float*)d_in[20];
    const float* fin_g    = (const float*)d_in[21];
    const float* fin_b    = (const float*)d_in[22];

    char* ws = (char*)d_ws;
    size_t off = 0;
    auto alloc = [&](size_t bytes) -> char* {
        char* p = ws + off;
        off += (bytes + 255) & ~(size_t)255;
        return p;
    };
    typedef unsigned short u16;
    u16*   wg1t   = (u16*)  alloc(2048ull * 1280 * 2);
    u16*   wg2t   = (u16*)  alloc(1024ull * 2048 * 2);
    u16*   wqkvl  = (u16*)  alloc(6ull * 3072 * 1024 * 2);
    u16*   wkvm   = (u16*)  alloc(6ull * 2048 * 1024 * 2);
    u16*   wot    = (u16*)  alloc(6ull * 1024 * 1024 * 2);
    u16*   wf1t   = (u16*)  alloc(6ull * 4096 * 1024 * 2);
    u16*   wf2t   = (u16*)  alloc(6ull * 1024 * 4096 * 2);
    float* biaskv = (float*)alloc(6ull * 2048 * 4);
    float* bpart  = (float*)alloc(384ull * 256 * 4);
    float* xres   = (float*)alloc(2048ull * 1024 * 4);
    u16*   latn   = (u16*)  alloc(2048ull * 1024 * 2);
    u16*   qkvl   = (u16*)  alloc(2048ull * 3072 * 2);
    u16*   obuf   = (u16*)  alloc(2048ull * 1024 * 2);
    u16*   ffny   = (u16*)  alloc(2048ull * 1024 * 2);
    u16*   ffnmid = (u16*)  alloc(2048ull * 4096 * 2);
    u16*   bufB   = (u16*)  alloc(32768ull * 1024 * 2);   // goal output, bf16
    u16*   bufC   = (u16*)  alloc(41943040ull * 2);       // x_f bf16, then nf
    if (off > ws_size) return;
    // bufA last: grouped-KV buffer. Pick largest G in {6,3,2,1} that fits.
    const size_t singleBytes = 32768ull * 2048 * 2;       // per-layer KV = 134 MB
    int G = 1;
    if (off + 6 * singleBytes <= ws_size)      G = 6;
    else if (off + 3 * singleBytes <= ws_size) G = 3;
    else if (off + 2 * singleBytes <= ws_size) G = 2;
    u16* bufA = (u16*)alloc((size_t)G * singleBytes);
    if (off > ws_size) return;
    const int kvN = G * 2048;

    // ---- phase 0: conversions / folds ----
    convert_bf16<<<40960, 256, 0, stream>>>(x_f, bufC, 41943040ull / 4);
    transpose_w<<<dim3(32, 20, 1), 256, 0, stream>>>(goal_w1, wg1t, nullptr, 1.f, 1280, 2048, 0, 0, 0);
    transpose_w<<<dim3(16, 32, 1), 256, 0, stream>>>(goal_w2, wg2t, nullptr, 1.f, 2048, 1024, 0, 0, 0);
    transpose_w<<<dim3(16, 16, 6), 256, 0, stream>>>(wq, wqkvl,                nullptr, 0.125f, 1024, 1024, 1024ull*1024, 3072ull*1024, 0);
    transpose_w<<<dim3(16, 16, 6), 256, 0, stream>>>(wk, wqkvl + 1024ull*1024, nullptr, 1.f,    1024, 1024, 1024ull*1024, 3072ull*1024, 0);
    transpose_w<<<dim3(16, 16, 6), 256, 0, stream>>>(wv, wqkvl + 2048ull*1024, nullptr, 1.f,    1024, 1024, 1024ull*1024, 3072ull*1024, 0);
    transpose_w<<<dim3(16, 16, 6), 256, 0, stream>>>(wk, wkvm,                 lnm_g,   1.f,    1024, 1024, 1024ull*1024, 2048ull*1024, 1024);
    transpose_w<<<dim3(16, 16, 6), 256, 0, stream>>>(wv, wkvm + 1024ull*1024,  lnm_g,   1.f,    1024, 1024, 1024ull*1024, 2048ull*1024, 1024);
    transpose_w<<<dim3(16, 16, 6), 256, 0, stream>>>(wo, wot,                  nullptr, 1.f,    1024, 1024, 1024ull*1024, 1024ull*1024, 0);
    transpose_w<<<dim3(64, 16, 6), 256, 0, stream>>>(ffw1, wf1t,               nullptr, 1.f,    1024, 4096, 4096ull*1024, 4096ull*1024, 0);
    transpose_w<<<dim3(16, 64, 6), 256, 0, stream>>>(ffw2, wf2t,               nullptr, 1.f,    4096, 1024, 4096ull*1024, 4096ull*1024, 0);
    fold_bias_part<<<dim3(48, 8), 256, 0, stream>>>(wk, wv, lnm_b, bpart);
    fold_bias_red<<<48, 256, 0, stream>>>(bpart, biaskv);
    init_x<<<2048, 256, 0, stream>>>(latents, xres);

    // ---- goal MLP ----
    gemm_bt<E_BIAS_GELU_BF16, 0><<<256 * 16, 256, 0, stream>>>(bufC, wg1t, bufA, goal_b1, nullptr, nullptr, 32768, 2048, 1280);
    gemm_bt<E_BIAS_TPOS_BF16, 0><<<256 * 8, 256, 0, stream>>>(bufA, wg2t, bufB, goal_b2, nullptr, tpos, 32768, 1024, 2048);
    ln_k<false, true, true><<<32768, 256, 0, stream>>>(bufB, nullptr, nullptr, bufC);   // nf

    // ---- depth loop (grouped KV: one merged GEMM per G layers, blocked layout) ----
    for (int i = 0; i < 6; ++i) {
        const u16* wqkvl_i = wqkvl + (size_t)i * 3072 * 1024;
        const u16* wot_i   = wot   + (size_t)i * 1024 * 1024;
        const u16* wf1_i   = wf1t  + (size_t)i * 4096 * 1024;
        const u16* wf2_i   = wf2t  + (size_t)i * 1024 * 4096;

        if ((i % G) == 0) {
            gemm_bt<E_BIAS_BF16, 1><<<G * 4096, 256, 0, stream>>>(
                bufC, wkvm + (size_t)i * 2048 * 1024, bufA,
                biaskv + i * 2048, nullptr, nullptr, 32768, kvN, 1024);
        }

        ln_k<true, true, false><<<2048, 256, 0, stream>>>(xres, lnl_g + i * 1024, lnl_b + i * 1024, latn);
        gemm64<E_BF16><<<32 * 24, 256, 0, stream>>>(latn, wqkvl_i, qkvl, nullptr, nullptr, 2048, 3072, 1024);
        attn_k<<<2048, 256, 0, stream>>>(qkvl, bufA + (size_t)(2 * (i % G)) * KV_PSLOT, obuf);
        gemm3232<E_ADD_F32><<<32 * 16, 256, 0, stream>>>(obuf, wot_i, xres, nullptr, xres, 2048, 1024, 1024);
        ln_k<true, true, false><<<2048, 256, 0, stream>>>(xres, ffn_g + i * 1024, ffn_b + i * 1024, ffny);
        gemm64<E_BIAS_GELU_BF16><<<32 * 32, 256, 0, stream>>>(ffny, wf1_i, ffnmid, ffb1 + i * 4096, nullptr, 2048, 4096, 1024);
        gemm3232<E_BIAS_ADD_F32><<<32 * 16, 256, 0, stream>>>(ffnmid, wf2_i, xres, ffb2 + i * 1024, xres, 2048, 1024, 4096);
    }

    // ---- final LN -> d_out (f32) ----
    ln_k<true, false, false><<<2048, 256, 0, stream>>>(xres, fin_g, fin_b, d_out);
}

// Round 20
// 2622.596 us; speedup vs baseline: 1.0354x; 1.0010x over previous
//
#include <hip/hip_runtime.h>
#include <math.h>

#define DEV __device__ __forceinline__

typedef __attribute__((ext_vector_type(8))) short short8;
typedef __attribute__((ext_vector_type(4))) short short4v;
typedef __attribute__((ext_vector_type(4))) float f32x4;
typedef __attribute__((ext_vector_type(8))) __bf16 bf16x8;

DEV float bf2f(unsigned short u) {
    union { unsigned int i; float f; } c; c.i = ((unsigned int)u) << 16; return c.f;
}
DEV unsigned short f2bf(float f) {
    union { float f; unsigned int i; } c; c.f = f;
    unsigned int u = c.i;
    u += 0x7fffu + ((u >> 16) & 1u);   // RNE
    return (unsigned short)(u >> 16);
}
DEV float gelu_exact(float x) { return 0.5f * x * (1.0f + erff(x * 0.70710678118654752f)); }

DEV f32x4 MF(bf16x8 a, bf16x8 b, f32x4 c) {
    return __builtin_amdgcn_mfma_f32_16x16x32_bf16(a, b, c, 0, 0, 0);
}

#define GLL16(g, l)                                                                   \
    __builtin_amdgcn_global_load_lds(                                                \
        (const __attribute__((address_space(1))) unsigned int*)(g),                  \
        (__attribute__((address_space(3))) unsigned int*)(l), 16, 0, 0)

// lgkm-only barrier (m201 pattern): drains DS ops but leaves global loads
// in flight across the barrier (T14 async-stage prerequisite).
#define BARL() do { asm volatile("s_waitcnt lgkmcnt(0)" ::: "memory");                \
                    __builtin_amdgcn_s_barrier(); } while (0)

// blocked-KV geometry: per (layer,part) slot = 128 bt x 16 h x 256 f x 64 d u16
#define KV_HSTR   16384ull                 // h stride (256*64)
#define KV_BTSTR  262144ull                // bt stride (16*16384)
#define KV_PSLOT  33554432ull              // (s*2+p) slot stride (128*262144)

// ---------------------------------------------------------------------------
// Weight transpose + f32->bf16 convert: in (K,N) f32 row-major -> out (N,K) bf16.
// ---------------------------------------------------------------------------
__global__ __launch_bounds__(256)
void transpose_w(const float* __restrict__ in, unsigned short* __restrict__ out,
                 const float* __restrict__ rowscale, float uscale,
                 int K, int N, size_t inStride, size_t outStride, int scaleStride)
{
    __shared__ float tile[64][65];
    in  += (size_t)blockIdx.z * inStride;
    out += (size_t)blockIdx.z * outStride;
    const int k0 = blockIdx.y * 64, n0 = blockIdx.x * 64;
    const int tid = threadIdx.x;
    const int c = tid & 63;
#pragma unroll
    for (int i = 0; i < 16; ++i) {
        int rr = (i << 2) + (tid >> 6);
        float v = in[(size_t)(k0 + rr) * N + n0 + c];
        if (rowscale) v *= rowscale[(size_t)blockIdx.z * scaleStride + k0 + rr];
        tile[rr][c] = v * uscale;
    }
    __syncthreads();
#pragma unroll
    for (int i = 0; i < 16; ++i) {
        int rr = (i << 2) + (tid >> 6);
        out[(size_t)(n0 + rr) * K + k0 + c] = f2bf(tile[c][rr]);
    }
}

// K-split partial: bpart[(blk48*8 + ks)*256 + tid] = sum over 128 rows
__global__ __launch_bounds__(256)
void fold_bias_part(const float* __restrict__ wk, const float* __restrict__ wv,
                    const float* __restrict__ bmed, float* __restrict__ bpart)
{
    const int d = blockIdx.x >> 3;
    const int rem = blockIdx.x & 7;
    const int part = rem >> 2;
    const int chunk = rem & 3;
    const int r0 = blockIdx.y * 128;
    const float* w = (part ? wv : wk) + (size_t)d * 1024 * 1024 + chunk * 256 + threadIdx.x;
    const float* b = bmed + d * 1024;
    float acc = 0.f;
    for (int r = r0; r < r0 + 128; ++r) acc += b[r] * w[(size_t)r * 1024];
    bpart[(size_t)(blockIdx.x * 8 + blockIdx.y) * 256 + threadIdx.x] = acc;
}

// deterministic reduce of the 8 k-slices
__global__ __launch_bounds__(256)
void fold_bias_red(const float* __restrict__ bpart, float* __restrict__ biaskv)
{
    const int d = blockIdx.x >> 3;
    const int rem = blockIdx.x & 7;
    const int part = rem >> 2;
    const int chunk = rem & 3;
    float acc = 0.f;
#pragma unroll
    for (int k = 0; k < 8; ++k)
        acc += bpart[(size_t)(blockIdx.x * 8 + k) * 256 + threadIdx.x];
    biaskv[d * 2048 + part * 1024 + chunk * 256 + threadIdx.x] = acc;
}

__global__ __launch_bounds__(256)
void convert_bf16(const float* __restrict__ in, unsigned short* __restrict__ out, size_t n4)
{
    size_t i = (size_t)blockIdx.x * 256 + threadIdx.x;
    if (i >= n4) return;
    float4 v = ((const float4*)in)[i];
    ushort4 u;
    u.x = f2bf(v.x); u.y = f2bf(v.y); u.z = f2bf(v.z); u.w = f2bf(v.w);
    ((ushort4*)out)[i] = u;
}

__global__ __launch_bounds__(256)
void init_x(const float* __restrict__ lat, float* __restrict__ x)
{
    const int row = blockIdx.x;
    ((float4*)x)[(size_t)row * 256 + threadIdx.x] =
        ((const float4*)lat)[(size_t)(row & 255) * 256 + threadIdx.x];
}

// ---------------------------------------------------------------------------
// LayerNorm over D=1024, one row per block. INBF: input is bf16 (u16).
// ---------------------------------------------------------------------------
template<bool AFFINE, bool OUTBF, bool INBF>
__global__ __launch_bounds__(256)
void ln_k(const void* __restrict__ in_, const float* __restrict__ g,
          const float* __restrict__ b, void* __restrict__ out)
{
    const int row = blockIdx.x;
    const int tid = threadIdx.x;
    float4 v;
    if (INBF) {
        ushort4 u = ((const ushort4*)((const unsigned short*)in_ + (size_t)row * 1024))[tid];
        v.x = bf2f(u.x); v.y = bf2f(u.y); v.z = bf2f(u.z); v.w = bf2f(u.w);
    } else {
        v = ((const float4*)((const float*)in_ + (size_t)row * 1024))[tid];
    }
    float s  = v.x + v.y + v.z + v.w;
    float ss = v.x * v.x + v.y * v.y + v.z * v.z + v.w * v.w;
#pragma unroll
    for (int o = 32; o > 0; o >>= 1) { s += __shfl_down(s, o); ss += __shfl_down(ss, o); }
    __shared__ float red[8];
    if ((tid & 63) == 0) { red[tid >> 6] = s; red[4 + (tid >> 6)] = ss; }
    __syncthreads();
    const float sum  = red[0] + red[1] + red[2] + red[3];
    const float ssum = red[4] + red[5] + red[6] + red[7];
    const float mean = sum * (1.0f / 1024.0f);
    const float var  = ssum * (1.0f / 1024.0f) - mean * mean;
    const float rs   = rsqrtf(var + 1e-5f);
    float o0 = (v.x - mean) * rs, o1 = (v.y - mean) * rs;
    float o2 = (v.z - mean) * rs, o3 = (v.w - mean) * rs;
    if (AFFINE) {
        float4 gv = ((const float4*)g)[tid];
        float4 bv = ((const float4*)b)[tid];
        o0 = o0 * gv.x + bv.x; o1 = o1 * gv.y + bv.y;
        o2 = o2 * gv.z + bv.z; o3 = o3 * gv.w + bv.w;
    }
    if (OUTBF) {
        ushort4 u; u.x = f2bf(o0); u.y = f2bf(o1); u.z = f2bf(o2); u.w = f2bf(o3);
        ((ushort4*)out)[(size_t)row * 256 + tid] = u;
    } else {
        float4 ov; ov.x = o0; ov.y = o1; ov.z = o2; ov.w = o3;
        ((float4*)out)[(size_t)row * 256 + tid] = ov;
    }
}

enum { E_BF16 = 0, E_BIAS_BF16, E_BIAS_GELU_BF16, E_BIAS_TPOS_BF16, E_ADD_F32, E_BIAS_ADD_F32 };

// ---------------------------------------------------------------------------
// Big-shape GEMM: 128x128 tile, BK=64, 4 waves, 32 KB LDS (~3 blocks/CU),
// global_load_lds with pre-swizzled source, conflict-free swizzled
// ds_read_b128 (cp = c ^ (row&7)), bijective XCD swizzle.
// MODE 0: flat output. MODE 1 ("grouped KV", measured 1.63x faster/layer):
// N = G*2048, grid = G*4096; per-XCD iteration s-group -> by -> bx keeps each
// group's B panel L2-resident. MODE-1 epilogue writes HEAD-BLOCKED layout
// [(s*2+p)*128+bt][h][f][d] so attention reads contiguous 32 KB tiles.
// C(M,N) = A(M,K) @ Bt(N,K)^T.
// ---------------------------------------------------------------------------
template<int EPI, int MODE>
__global__ __launch_bounds__(256, 2)
void gemm_bt(const unsigned short* __restrict__ A, const unsigned short* __restrict__ Bt,
             void* __restrict__ Out,
             const float* __restrict__ bias, const float* __restrict__ addsrc,
             const float* __restrict__ tpos,
             int M, int N, int K)
{
    __shared__ unsigned short lds[2 * 128 * 64];
    const int tid  = threadIdx.x;
    const int wave = tid >> 6, lane = tid & 63;
    const int nbx  = N >> 7;

    int by, bx;
    if (MODE == 1) {
        const int u = blockIdx.x >> 3;
        const int s = u >> 9;                  // depth group
        const int v = u & 511;
        by = (blockIdx.x & 7) * 32 + (v >> 4); // 0..255
        bx = s * 16 + (v & 15);
    } else {
        const int nwg = gridDim.x;
        int bid = blockIdx.x;
        int wg = ((nwg & 7) == 0) ? ((bid & 7) * (nwg >> 3) + (bid >> 3)) : bid;
        by = wg / nbx; bx = wg % nbx;
    }

    const int swz = ((lane & 7) ^ (lane >> 3)) * 8;
    const unsigned short* gA = A  + (size_t)(by * 128 + (lane >> 3)) * K + swz;
    const unsigned short* gB = Bt + (size_t)(bx * 128 + (lane >> 3)) * K + swz;

    const int wr = wave >> 1, wc = wave & 1;
    f32x4 acc[4][4] = {};

    unsigned short* ldsA = lds;
    unsigned short* ldsB = lds + 128 * 64;

    const int off0 = (((lane >> 4)    ) ^ (lane & 7)) * 8;
    const int off1 = (((lane >> 4) | 4) ^ (lane & 7)) * 8;
    const unsigned short* la = ldsA + (wr * 64 + (lane & 15)) * 64;
    const unsigned short* lb = ldsB + (wc * 64 + (lane & 15)) * 64;

    for (int kt = 0; kt < K; kt += 64) {
#pragma unroll
        for (int j = 0; j < 4; ++j) {
            const int chunk = (j << 2) + wave;   // wave-uniform
            GLL16(gA + (size_t)chunk * 8 * K + kt, ldsA + chunk * 512);
            GLL16(gB + (size_t)chunk * 8 * K + kt, ldsB + chunk * 512);
        }
        __syncthreads();
#pragma unroll
        for (int kk = 0; kk < 2; ++kk) {
            const int offk = kk ? off1 : off0;
            bf16x8 a[4], b[4];
#pragma unroll
            for (int m = 0; m < 4; ++m) a[m] = *(const bf16x8*)(la + m * 1024 + offk);
#pragma unroll
            for (int n = 0; n < 4; ++n) b[n] = *(const bf16x8*)(lb + n * 1024 + offk);
#pragma unroll
            for (int m = 0; m < 4; ++m)
#pragma unroll
                for (int n = 0; n < 4; ++n)
                    acc[m][n] = MF(a[m], b[n], acc[m][n]);
        }
        __syncthreads();
    }

    // epilogue: C/D layout col = lane&15, row = (lane>>4)*4 + reg  [m89-verified]
    const int r0 = by * 128 + wr * 64 + (lane >> 4) * 4;
    const int c0 = bx * 128 + wc * 64 + (lane & 15);
#pragma unroll
    for (int m = 0; m < 4; ++m) {
#pragma unroll
        for (int n = 0; n < 4; ++n) {
            const int c = c0 + n * 16;
            float bv = 0.f;
            if (EPI == E_BIAS_BF16 || EPI == E_BIAS_GELU_BF16 ||
                EPI == E_BIAS_TPOS_BF16 || EPI == E_BIAS_ADD_F32)
                bv = bias[c];
            // blocked-KV decomposition (MODE 1)
            const int s  = c >> 11;
            const int cx = c & 2047;
            const int p  = cx >> 10, hx = (cx >> 6) & 15, d = cx & 63;
#pragma unroll
            for (int j = 0; j < 4; ++j) {
                const int r = r0 + m * 16 + j;
                float v = acc[m][n][j] + bv;
                if (EPI == E_BIAS_GELU_BF16) v = gelu_exact(v);
                if (EPI == E_BIAS_TPOS_BF16) v += tpos[(((unsigned)r >> 8) & 15) * 1024 + c];
                if (EPI == E_ADD_F32 || EPI == E_BIAS_ADD_F32) v += addsrc[(size_t)r * N + c];
                if (MODE == 1) {
                    const int bt = r >> 8, f = r & 255;
                    ((unsigned short*)Out)[(size_t)((s * 2 + p) * 128 + bt) * KV_BTSTR +
                                           (size_t)hx * KV_HSTR + f * 64 + d] = f2bf(v);
                } else if (EPI == E_ADD_F32 || EPI == E_BIAS_ADD_F32) {
                    ((float*)Out)[(size_t)r * N + c] = v;
                } else {
                    ((unsigned short*)Out)[(size_t)r * N + c] = f2bf(v);
                }
            }
        }
    }
}

// ---------------------------------------------------------------------------
// Latent-stack GEMM: 64x128 tile, BK=64, 4 waves, 24 KB LDS, m97 skeleton +
// zero-conflict swizzle (r4-verified). Used for qkv (grid 768), ffn1 (1024).
// ---------------------------------------------------------------------------
template<int EPI>
__global__ __launch_bounds__(256, 4)
void gemm64(const unsigned short* __restrict__ A, const unsigned short* __restrict__ Bt,
            void* __restrict__ Out,
            const float* __restrict__ bias, const float* __restrict__ addsrc,
            int M, int N, int K)
{
    __shared__ unsigned short lds[64 * 64 + 128 * 64];
    const int tid  = threadIdx.x;
    const int wave = tid >> 6, lane = tid & 63;
    const int nbx  = N >> 7;

    const int nwg = gridDim.x;
    int bid = blockIdx.x;
    int wg = ((nwg & 7) == 0) ? ((bid & 7) * (nwg >> 3) + (bid >> 3)) : bid;
    const int by = wg / nbx, bx = wg % nbx;

    const int swz = ((lane & 7) ^ (lane >> 3)) * 8;
    const unsigned short* gA = A  + (size_t)(by * 64  + (lane >> 3)) * K + swz;
    const unsigned short* gB = Bt + (size_t)(bx * 128 + (lane >> 3)) * K + swz;

    const int wr = wave >> 1, wc = wave & 1;
    f32x4 acc[2][4] = {};

    unsigned short* ldsA = lds;
    unsigned short* ldsB = lds + 64 * 64;

    const int off0 = (((lane >> 4)    ) ^ (lane & 7)) * 8;
    const int off1 = (((lane >> 4) | 4) ^ (lane & 7)) * 8;
    const unsigned short* la = ldsA + (wr * 32 + (lane & 15)) * 64;
    const unsigned short* lb = ldsB + (wc * 64 + (lane & 15)) * 64;

    for (int kt = 0; kt < K; kt += 64) {
        GLL16(gA + (size_t)(wave)     * 8 * K + kt, ldsA + (wave)      * 512);
        GLL16(gA + (size_t)(4 + wave) * 8 * K + kt, ldsA + (4 + wave)  * 512);
#pragma unroll
        for (int j = 0; j < 4; ++j) {
            const int chunk = (j << 2) + wave;
            GLL16(gB + (size_t)chunk * 8 * K + kt, ldsB + chunk * 512);
        }
        __syncthreads();
#pragma unroll
        for (int kk = 0; kk < 2; ++kk) {
            const int offk = kk ? off1 : off0;
            bf16x8 a[2], b[4];
#pragma unroll
            for (int m = 0; m < 2; ++m) a[m] = *(const bf16x8*)(la + m * 1024 + offk);
#pragma unroll
            for (int n = 0; n < 4; ++n) b[n] = *(const bf16x8*)(lb + n * 1024 + offk);
#pragma unroll
            for (int m = 0; m < 2; ++m)
#pragma unroll
                for (int n = 0; n < 4; ++n)
                    acc[m][n] = MF(a[m], b[n], acc[m][n]);
        }
        __syncthreads();
    }

    const int r0 = by * 64 + wr * 32 + (lane >> 4) * 4;
    const int c0 = bx * 128 + wc * 64 + (lane & 15);
#pragma unroll
    for (int m = 0; m < 2; ++m) {
#pragma unroll
        for (int n = 0; n < 4; ++n) {
            const int c = c0 + n * 16;
#pragma unroll
            for (int j = 0; j < 4; ++j) {
                const int r = r0 + m * 16 + j;
                float v = acc[m][n][j];
                if (EPI == E_BIAS_BF16 || EPI == E_BIAS_GELU_BF16 || EPI == E_BIAS_ADD_F32)
                    v += bias[c];
                if (EPI == E_BIAS_GELU_BF16) v = gelu_exact(v);
                if (EPI == E_ADD_F32 || EPI == E_BIAS_ADD_F32) v += addsrc[(size_t)r * N + c];
                if (EPI == E_ADD_F32 || EPI == E_BIAS_ADD_F32)
                    ((float*)Out)[(size_t)r * N + c] = v;
                else
                    ((unsigned short*)Out)[(size_t)r * N + c] = f2bf(v);
            }
        }
    }
}

// ---------------------------------------------------------------------------
// Small-N GEMM: 64x64 tile, BK=64, 4 waves (wave-tile 32x32), 16 KB LDS ->
// 4 blocks/CU. For wo and ffn2 (N=1024): grid 512 (r9/r11 A/B-measured best).
// ---------------------------------------------------------------------------
template<int EPI>
__global__ __launch_bounds__(256, 4)
void gemm3232(const unsigned short* __restrict__ A, const unsigned short* __restrict__ Bt,
              void* __restrict__ Out,
              const float* __restrict__ bias, const float* __restrict__ addsrc,
              int M, int N, int K)
{
    __shared__ unsigned short lds[2 * 64 * 64];    // A then B, 16 KiB
    const int tid  = threadIdx.x;
    const int wave = tid >> 6, lane = tid & 63;
    const int nbx  = N >> 6;

    const int nwg = gridDim.x;
    int bid = blockIdx.x;
    int wg = ((nwg & 7) == 0) ? ((bid & 7) * (nwg >> 3) + (bid >> 3)) : bid;
    const int by = wg / nbx, bx = wg % nbx;

    const int swz = ((lane & 7) ^ (lane >> 3)) * 8;
    const unsigned short* gA = A  + (size_t)(by * 64 + (lane >> 3)) * K + swz;
    const unsigned short* gB = Bt + (size_t)(bx * 64 + (lane >> 3)) * K + swz;

    const int wr = wave >> 1, wc = wave & 1;
    f32x4 acc[2][2] = {};

    unsigned short* ldsA = lds;
    unsigned short* ldsB = lds + 64 * 64;

    const int off0 = (((lane >> 4)    ) ^ (lane & 7)) * 8;
    const int off1 = (((lane >> 4) | 4) ^ (lane & 7)) * 8;
    const unsigned short* la = ldsA + (wr * 32 + (lane & 15)) * 64;
    const unsigned short* lb = ldsB + (wc * 32 + (lane & 15)) * 64;

    for (int kt = 0; kt < K; kt += 64) {
        GLL16(gA + (size_t)(wave)     * 8 * K + kt, ldsA + (wave)      * 512);
        GLL16(gA + (size_t)(4 + wave) * 8 * K + kt, ldsA + (4 + wave)  * 512);
        GLL16(gB + (size_t)(wave)     * 8 * K + kt, ldsB + (wave)      * 512);
        GLL16(gB + (size_t)(4 + wave) * 8 * K + kt, ldsB + (4 + wave)  * 512);
        __syncthreads();
#pragma unroll
        for (int kk = 0; kk < 2; ++kk) {
            const int offk = kk ? off1 : off0;
            bf16x8 a[2], b[2];
#pragma unroll
            for (int m = 0; m < 2; ++m) a[m] = *(const bf16x8*)(la + m * 1024 + offk);
#pragma unroll
            for (int n = 0; n < 2; ++n) b[n] = *(const bf16x8*)(lb + n * 1024 + offk);
#pragma unroll
            for (int m = 0; m < 2; ++m)
#pragma unroll
                for (int n = 0; n < 2; ++n)
                    acc[m][n] = MF(a[m], b[n], acc[m][n]);
        }
        __syncthreads();
    }

    const int r0 = by * 64 + wr * 32 + (lane >> 4) * 4;
    const int c0 = bx * 64 + wc * 32 + (lane & 15);
#pragma unroll
    for (int m = 0; m < 2; ++m) {
#pragma unroll
        for (int n = 0; n < 2; ++n) {
            const int c = c0 + n * 16;
#pragma unroll
            for (int j = 0; j < 4; ++j) {
                const int r = r0 + m * 16 + j;
                float v = acc[m][n][j];
                if (EPI == E_BIAS_BF16 || EPI == E_BIAS_GELU_BF16 || EPI == E_BIAS_ADD_F32)
                    v += bias[c];
                if (EPI == E_BIAS_GELU_BF16) v = gelu_exact(v);
                if (EPI == E_ADD_F32 || EPI == E_BIAS_ADD_F32) v += addsrc[(size_t)r * N + c];
                if (EPI == E_ADD_F32 || EPI == E_BIAS_ADD_F32)
                    ((float*)Out)[(size_t)r * N + c] = v;
                else
                    ((unsigned short*)Out)[(size_t)r * N + c] = f2bf(v);
            }
        }
    }
}

// ---------------------------------------------------------------------------
// Attention v4 (T14 async-V + vectorized LDS reads): one block per (bt, head).
// Q=16, F=272, DH=64. sim stride 276 (f32x4-aligned); PV unrolled x4 with one
// float4 sim read per 4 V-rows; qs read as 2x float4 per d-step. Media KV
// read from head-blocked layout (contiguous 32 KB per tile).
// ---------------------------------------------------------------------------
__global__ __launch_bounds__(256)
void attn_k(const unsigned short* __restrict__ qkvl, const unsigned short* __restrict__ kbase,
            unsigned short* __restrict__ o)
{
    __shared__ unsigned short kv[272 * 72];
    __shared__ float sim[16 * 276];
    __shared__ float qs[16 * 68];
    __shared__ float red[64];

    const int bt = blockIdx.x >> 4, h = blockIdx.x & 15;
    const int tid = threadIdx.x;
    const int lane = tid & 63, wave = tid >> 6;
    const int r = tid & 15, grp = tid >> 4;

    const unsigned short* kt = kbase + (size_t)bt * KV_BTSTR + (size_t)h * KV_HSTR;

    {
        const int qi = tid >> 4, d0 = (tid & 15) * 4;
        const unsigned short* src = qkvl + (size_t)(bt * 16 + qi) * 3072 + h * 64 + d0;
        qs[qi * 68 + d0 + 0] = bf2f(src[0]);
        qs[qi * 68 + d0 + 1] = bf2f(src[1]);
        qs[qi * 68 + d0 + 2] = bf2f(src[2]);
        qs[qi * 68 + d0 + 3] = bf2f(src[3]);
    }
    // stage K into LDS
#pragma unroll
    for (int i = 0; i < 9; ++i) {
        int idx = i * 256 + tid;
        if (idx < 2176) {
            int f = idx >> 3, cp = idx & 7;
            const unsigned short* src = (f < 256)
                ? kt + f * 64 + cp * 8
                : qkvl + (size_t)(bt * 16 + (f - 256)) * 3072 + 1024 + h * 64 + cp * 8;
            *(short8*)&kv[f * 72 + cp * 8] = *(const short8*)src;
        }
    }
    // T14: issue V loads now (into registers); they stay in flight across the
    // lgkm-only barriers and drain just before the V ds_write phase.
    short8 vreg[9];
#pragma unroll
    for (int i = 0; i < 9; ++i) {
        int idx = i * 256 + tid;
        if (idx < 2176) {
            int f = idx >> 3, cp = idx & 7;
            const unsigned short* src = (f < 256)
                ? kt + KV_PSLOT + f * 64 + cp * 8
                : qkvl + (size_t)(bt * 16 + (f - 256)) * 3072 + 2048 + h * 64 + cp * 8;
            vreg[i] = *(const short8*)src;
        }
    }
    BARL();                                        // S0: q/K LDS writes drained

    float p[17];
#pragma unroll
    for (int i = 0; i < 17; ++i) p[i] = 0.f;
#pragma unroll
    for (int d = 0; d < 64; d += 8) {
        float4 qa = *(const float4*)&qs[r * 68 + d];
        float4 qb = *(const float4*)&qs[r * 68 + d + 4];
        float q8[8] = { qa.x, qa.y, qa.z, qa.w, qb.x, qb.y, qb.z, qb.w };
#pragma unroll
        for (int i = 0; i < 17; ++i) {
            short8 k8 = *(const short8*)&kv[(grp + i * 16) * 72 + d];
#pragma unroll
            for (int j = 0; j < 8; ++j) p[i] += q8[j] * bf2f((unsigned short)k8[j]);
        }
    }
    float mx = -3.0e38f;
#pragma unroll
    for (int i = 0; i < 17; ++i) mx = fmaxf(mx, p[i]);
    mx = fmaxf(mx, __shfl_xor(mx, 16));
    mx = fmaxf(mx, __shfl_xor(mx, 32));
    if (lane < 16) red[wave * 16 + lane] = mx;
    BARL();                                        // S1: dots done, red(max) ready
    const float rowmax = fmaxf(fmaxf(red[r], red[16 + r]), fmaxf(red[32 + r], red[48 + r]));

    float sm = 0.f;
#pragma unroll
    for (int i = 0; i < 17; ++i) { p[i] = __expf(p[i] - rowmax); sm += p[i]; }
    sm += __shfl_xor(sm, 16);
    sm += __shfl_xor(sm, 32);
#pragma unroll
    for (int i = 0; i < 17; ++i) sim[r * 276 + grp + i * 16] = p[i];
    BARL();                                        // S2: red(max) reads done
    if (lane < 16) red[wave * 16 + lane] = sm;
    // V: pure ds_writes from registers (vmcnt waits auto-inserted on vreg)
#pragma unroll
    for (int i = 0; i < 9; ++i) {
        int idx = i * 256 + tid;
        if (idx < 2176) {
            int f = idx >> 3, cp = idx & 7;
            *(short8*)&kv[f * 72 + cp * 8] = vreg[i];
        }
    }
    BARL();                                        // S3: sim + red(sum) + V ready
    const float inv = 1.0f / (red[r] + red[16 + r] + red[32 + r] + red[48 + r]);

    float o0 = 0.f, o1 = 0.f, o2 = 0.f, o3 = 0.f;
    for (int f = 0; f < 272; f += 4) {
        float4 pv4 = *(const float4*)&sim[r * 276 + f];
#pragma unroll
        for (int k = 0; k < 4; ++k) {
            const float pv = (k == 0) ? pv4.x : (k == 1) ? pv4.y : (k == 2) ? pv4.z : pv4.w;
            short4v v4 = *(const short4v*)&kv[(f + k) * 72 + grp * 4];
            o0 += pv * bf2f((unsigned short)v4[0]);
            o1 += pv * bf2f((unsigned short)v4[1]);
            o2 += pv * bf2f((unsigned short)v4[2]);
            o3 += pv * bf2f((unsigned short)v4[3]);
        }
    }
    unsigned short* dst = o + (size_t)(bt * 16 + r) * 1024 + h * 64 + grp * 4;
    dst[0] = f2bf(o0 * inv);
    dst[1] = f2bf(o1 * inv);
    dst[2] = f2bf(o2 * inv);
    dst[3] = f2bf(o3 * inv);
}

// ---------------------------------------------------------------------------
extern "C" void kernel_launch(void* const* d_in, const int* in_sizes, int n_in,
                              void* d_out, int out_size, void* d_ws, size_t ws_size,
                              hipStream_t stream)
{
    const float* x_f      = (const float*)d_in[0];
    const float* goal_w1  = (const float*)d_in[1];
    const float* goal_b1  = (const float*)d_in[2];
    const float* goal_w2  = (const float*)d_in[3];
    const float* goal_b2  = (const float*)d_in[4];
    const float* latents  = (const float*)d_in[5];
    const float* tpos     = (const float*)d_in[6];
    const float* lnm_g    = (const float*)d_in[7];
    const float* lnm_b    = (const float*)d_in[8];
    const float* lnl_g    = (const float*)d_in[9];
    const float* lnl_b    = (const float*)d_in[10];
    const float* wq       = (const float*)d_in[11];
    const float* wk       = (const float*)d_in[12];
    const float* wv       = (const float*)d_in[13];
    const float* wo       = (const float*)d_in[14];
    const float* ffn_g    = (const float*)d_in[15];
    const float* ffn_b    = (const float*)d_in[16];
    const float* ffw1     = (const float*)d_in[17];
    const float* ffb1     = (const float*)d_in[18];
    const float* ffw2     = (const float*)d_in[19];
    const float* ffb2     = (const float*)d_in[20];
    const float* fin_g    = (const float*)d_in[21];
    const float* fin_b    = (const float*)d_in[22];

    char* ws = (char*)d_ws;
    size_t off = 0;
    auto alloc = [&](size_t bytes) -> char* {
        char* p = ws + off;
        off += (bytes + 255) & ~(size_t)255;
        return p;
    };
    typedef unsigned short u16;
    // NOTE: wg1t / wg2t / bufB are dead before the first KV GEMM; they are
    // aliased into bufA's head (below) to free ~76.5 MB for a larger KV group.
    u16*   wqkvl  = (u16*)  alloc(6ull * 3072 * 1024 * 2);
    u16*   wkvm   = (u16*)  alloc(6ull * 2048 * 1024 * 2);
    u16*   wot    = (u16*)  alloc(6ull * 1024 * 1024 * 2);
    u16*   wf1t   = (u16*)  alloc(6ull * 4096 * 1024 * 2);
    u16*   wf2t   = (u16*)  alloc(6ull * 1024 * 4096 * 2);
    float* biaskv = (float*)alloc(6ull * 2048 * 4);
    float* bpart  = (float*)alloc(384ull * 256 * 4);
    float* xres   = (float*)alloc(2048ull * 1024 * 4);
    u16*   latn   = (u16*)  alloc(2048ull * 1024 * 2);
    u16*   qkvl   = (u16*)  alloc(2048ull * 3072 * 2);
    u16*   obuf   = (u16*)  alloc(2048ull * 1024 * 2);
    u16*   ffny   = (u16*)  alloc(2048ull * 1024 * 2);
    u16*   ffnmid = (u16*)  alloc(2048ull * 4096 * 2);
    u16*   bufC   = (u16*)  alloc(41943040ull * 2);       // x_f bf16, then nf
    if (off > ws_size) return;
    // bufA last: grouped-KV buffer. Pick largest G in {6,3,2,1} that fits.
    const size_t singleBytes = 32768ull * 2048 * 2;       // per-layer KV = 134 MB
    int G = 1;
    if (off + 6 * singleBytes <= ws_size)      G = 6;
    else if (off + 3 * singleBytes <= ws_size) G = 3;
    else if (off + 2 * singleBytes <= ws_size) G = 2;
    u16* bufA = (u16*)alloc((size_t)G * singleBytes);
    if (off > ws_size) return;
    const int kvN = G * 2048;

    // aliases inside bufA (all dead before the first KV GEMM writes bufA):
    //   wg1t [0, 2621440) u16 ; wg2t [2621440, 4718592) ; bufB [4718592, 38273024)
    //   h1 (goal1 output, 32768x2048) at [38273024, 105381888) -- fits even G=2.
    u16* wg1t = bufA;
    u16* wg2t = bufA + 2621440;
    u16* bufB = bufA + 4718592;
    u16* h1   = bufA + 38273024;

    // ---- phase 0: conversions / folds ----
    convert_bf16<<<40960, 256, 0, stream>>>(x_f, bufC, 41943040ull / 4);
    transpose_w<<<dim3(32, 20, 1), 256, 0, stream>>>(goal_w1, wg1t, nullptr, 1.f, 1280, 2048, 0, 0, 0);
    transpose_w<<<dim3(16, 32, 1), 256, 0, stream>>>(goal_w2, wg2t, nullptr, 1.f, 2048, 1024, 0, 0, 0);
    transpose_w<<<dim3(16, 16, 6), 256, 0, stream>>>(wq, wqkvl,                nullptr, 0.125f, 1024, 1024, 1024ull*1024, 3072ull*1024, 0);
    transpose_w<<<dim3(16, 16, 6), 256, 0, stream>>>(wk, wqkvl + 1024ull*1024, nullptr, 1.f,    1024, 1024, 1024ull*1024, 3072ull*1024, 0);
    transpose_w<<<dim3(16, 16, 6), 256, 0, stream>>>(wv, wqkvl + 2048ull*1024, nullptr, 1.f,    1024, 1024, 1024ull*1024, 3072ull*1024, 0);
    transpose_w<<<dim3(16, 16, 6), 256, 0, stream>>>(wk, wkvm,                 lnm_g,   1.f,    1024, 1024, 1024ull*1024, 2048ull*1024, 1024);
    transpose_w<<<dim3(16, 16, 6), 256, 0, stream>>>(wv, wkvm + 1024ull*1024,  lnm_g,   1.f,    1024, 1024, 1024ull*1024, 2048ull*1024, 1024);
    transpose_w<<<dim3(16, 16, 6), 256, 0, stream>>>(wo, wot,                  nullptr, 1.f,    1024, 1024, 1024ull*1024, 1024ull*1024, 0);
    transpose_w<<<dim3(64, 16, 6), 256, 0, stream>>>(ffw1, wf1t,               nullptr, 1.f,    1024, 4096, 4096ull*1024, 4096ull*1024, 0);
    transpose_w<<<dim3(16, 64, 6), 256, 0, stream>>>(ffw2, wf2t,               nullptr, 1.f,    4096, 1024, 4096ull*1024, 4096ull*1024, 0);
    fold_bias_part<<<dim3(48, 8), 256, 0, stream>>>(wk, wv, lnm_b, bpart);
    fold_bias_red<<<48, 256, 0, stream>>>(bpart, biaskv);
    init_x<<<2048, 256, 0, stream>>>(latents, xres);

    // ---- goal MLP (h1 and all weight aliases live inside bufA; disjoint) ----
    gemm_bt<E_BIAS_GELU_BF16, 0><<<256 * 16, 256, 0, stream>>>(bufC, wg1t, h1, goal_b1, nullptr, nullptr, 32768, 2048, 1280);
    gemm_bt<E_BIAS_TPOS_BF16, 0><<<256 * 8, 256, 0, stream>>>(h1, wg2t, bufB, goal_b2, nullptr, tpos, 32768, 1024, 2048);
    ln_k<false, true, true><<<32768, 256, 0, stream>>>(bufB, nullptr, nullptr, bufC);   // nf

    // ---- depth loop (grouped KV: one merged GEMM per G layers, blocked layout) ----
    for (int i = 0; i < 6; ++i) {
        const u16* wqkvl_i = wqkvl + (size_t)i * 3072 * 1024;
        const u16* wot_i   = wot   + (size_t)i * 1024 * 1024;
        const u16* wf1_i   = wf1t  + (size_t)i * 4096 * 1024;
        const u16* wf2_i   = wf2t  + (size_t)i * 1024 * 4096;

        if ((i % G) == 0) {
            gemm_bt<E_BIAS_BF16, 1><<<G * 4096, 256, 0, stream>>>(
                bufC, wkvm + (size_t)i * 2048 * 1024, bufA,
                biaskv + i * 2048, nullptr, nullptr, 32768, kvN, 1024);
        }

        ln_k<true, true, false><<<2048, 256, 0, stream>>>(xres, lnl_g + i * 1024, lnl_b + i * 1024, latn);
        gemm64<E_BF16><<<32 * 24, 256, 0, stream>>>(latn, wqkvl_i, qkvl, nullptr, nullptr, 2048, 3072, 1024);
        attn_k<<<2048, 256, 0, stream>>>(qkvl, bufA + (size_t)(2 * (i % G)) * KV_PSLOT, obuf);
        gemm3232<E_ADD_F32><<<32 * 16, 256, 0, stream>>>(obuf, wot_i, xres, nullptr, xres, 2048, 1024, 1024);
        ln_k<true, true, false><<<2048, 256, 0, stream>>>(xres, ffn_g + i * 1024, ffn_b + i * 1024, ffny);
        gemm64<E_BIAS_GELU_BF16><<<32 * 32, 256, 0, stream>>>(ffny, wf1_i, ffnmid, ffb1 + i * 4096, nullptr, 2048, 4096, 1024);
        gemm3232<E_BIAS_ADD_F32><<<32 * 16, 256, 0, stream>>>(ffnmid, wf2_i, xres, ffb2 + i * 1024, xres, 2048, 1024, 4096);
    }

    // ---- final LN -> d_out (f32) ----
    ln_k<true, false, false><<<2048, 256, 0, stream>>>(xres, fin_g, fin_b, d_out);
}